// Round 1
// baseline (7083.466 us; speedup 1.0000x reference)
//
#include <hip/hip_runtime.h>
#include <hip/hip_cooperative_groups.h>

namespace cg = cooperative_groups;

typedef unsigned short u16;
typedef __attribute__((ext_vector_type(8))) u16 u16x8;
typedef __attribute__((ext_vector_type(4))) u16 u16x4;

#define NN 4096
#define NITER 50
#define REGE 10.0f
#define TAUV 1000.0f
#define AMARG (1.0f / 4096.0f)
#define EPSS 1e-16f

__device__ __forceinline__ float b2f(u16 h) {
    return __uint_as_float(((unsigned)h) << 16);
}
__device__ __forceinline__ u16 f2b(float f) {
    // round-to-nearest-even bf16; inputs are positive finite (exp outputs)
    unsigned x = __float_as_uint(f);
    return (u16)((x + 0x7FFFu + ((x >> 16) & 1u)) >> 16);
}
__device__ __forceinline__ float wsum(float v) {
#pragma unroll
    for (int off = 32; off; off >>= 1) v += __shfl_xor(v, off, 64);
    return v;
}

// Single cooperative kernel:
//  S0: row norms, vector init, flag/out init
//  S1: K0 = exp(-M/eps) bf16, plus transpose copy K0T (LDS-tiled 64x64 GEMM, d=64)
//  50x: P1 (t = K0T~u -> v, vt, Eb-absorb, v-flag) | P2 (s = K0 vt -> u, ut, Ea-absorb, u-flag)
//  F : loss = scale * sum_ij K0*( -eps*log K0 )*ut_i*vt_j
__global__ __launch_bounds__(256, 4) void sinkhorn_all(
    const float* __restrict__ x, const float* __restrict__ y, float* __restrict__ out,
    u16* __restrict__ K0, u16* __restrict__ K0T,
    float* __restrict__ xsq, float* __restrict__ ysq,
    float* __restrict__ Ea, float* __restrict__ Eb,
    float* __restrict__ uu, float* __restrict__ vv,
    float* __restrict__ ut, float* __restrict__ vt,
    int* __restrict__ flags) {
    cg::grid_group grid = cg::this_grid();
    __shared__ float xs[64][65];
    __shared__ float ys[64][65];
    __shared__ float red[4];

    const int tid  = threadIdx.x;
    const int lane = tid & 63;
    const int wid  = tid >> 6;
    const int gw   = blockIdx.x * 4 + wid;   // global wave id
    const int nw   = gridDim.x * 4;          // total waves

    // ---------------- S0: row squared norms + state init ----------------
    for (int r = gw; r < 2 * NN; r += nw) {
        const float* src = (r < NN) ? (x + (size_t)r * 64) : (y + (size_t)(r - NN) * 64);
        float t = src[lane];
        float s = wsum(t * t);
        if (lane == 0) {
            if (r < NN) xsq[r] = s; else ysq[r - NN] = s;
        }
    }
    for (int i = blockIdx.x * blockDim.x + tid; i < NN; i += gridDim.x * blockDim.x) {
        Ea[i] = 1.f; Eb[i] = 1.f;
        uu[i] = AMARG; vv[i] = AMARG;
        ut[i] = AMARG; vt[i] = AMARG;   // ut = Ea*u, vt = Eb*v
    }
    if (blockIdx.x == 0 && tid < 3) flags[tid] = 0;
    if (blockIdx.x == 0 && tid == 0) out[0] = 0.f;
    grid.sync();

    // ---------------- S1: K0 and K0T (bf16) ----------------
    {
        const int tx = tid & 15, ty = tid >> 4;
        for (int tile = blockIdx.x; tile < 64 * 64; tile += gridDim.x) {
            const int i0 = (tile >> 6) << 6;
            const int j0 = (tile & 63) << 6;
            __syncthreads();   // protect LDS reuse across tiles
            for (int e = tid; e < 4096; e += 256) {
                const int r = e >> 6, c = e & 63;
                xs[r][c] = x[(size_t)(i0 + r) * 64 + c];
                ys[r][c] = y[(size_t)(j0 + r) * 64 + c];
            }
            __syncthreads();
            float acc[4][4] = {};
#pragma unroll
            for (int k = 0; k < 64; ++k) {
                float xv[4], yv[4];
#pragma unroll
                for (int r = 0; r < 4; ++r) xv[r] = xs[ty * 4 + r][k];
#pragma unroll
                for (int c = 0; c < 4; ++c) yv[c] = ys[tx * 4 + c][k];
#pragma unroll
                for (int r = 0; r < 4; ++r)
#pragma unroll
                    for (int c = 0; c < 4; ++c)
                        acc[r][c] = __fmaf_rn(xv[r], yv[c], acc[r][c]);
            }
            u16 kb[4][4];
#pragma unroll
            for (int r = 0; r < 4; ++r) {
                const float xq = xsq[i0 + ty * 4 + r];
#pragma unroll
                for (int c = 0; c < 4; ++c) {
                    const float m = xq + ysq[j0 + tx * 4 + c] - 2.f * acc[r][c];
                    kb[r][c] = f2b(__expf(-m * (1.0f / REGE)));
                }
            }
#pragma unroll
            for (int r = 0; r < 4; ++r) {
                u16x4 pk = {kb[r][0], kb[r][1], kb[r][2], kb[r][3]};
                *(u16x4*)(K0 + (size_t)(i0 + ty * 4 + r) * NN + j0 + tx * 4) = pk;
            }
#pragma unroll
            for (int c = 0; c < 4; ++c) {
                u16x4 pk = {kb[0][c], kb[1][c], kb[2][c], kb[3][c]};
                *(u16x4*)(K0T + (size_t)(j0 + tx * 4 + c) * NN + i0 + ty * 4) = pk;
            }
        }
    }
    grid.sync();

    // ---------------- 50 Sinkhorn iterations ----------------
    const float4* ut4 = (const float4*)ut;
    const float4* vt4 = (const float4*)vt;

    for (int it = 0; it < NITER; ++it) {
        const int fprev = (it + 2) % 3;  // absorb flag of iteration it-1
        const int fcur  = it % 3;        // this iteration's flag (u/v > TAU)
        const int fnext = (it + 1) % 3;  // reset for next iteration
        const bool absorb = (*(volatile int*)(flags + fprev)) != 0;
        const float su = absorb ? AMARG : 1.f;  // absorbed ut is uniformly scaled by a
        if (tid == 0) *(volatile int*)(flags + fnext) = 0;

        // P1: per column j:  t_j = sum_i K0T[j][i]*ut[i];  v_j = b/(Eb_j*su*t_j + eps)
        for (int j = gw; j < NN; j += nw) {
            const u16x8* rowp = (const u16x8*)(K0T + (size_t)j * NN);
            float s = 0.f;
#pragma unroll
            for (int m = 0; m < 8; ++m) {
                const int c = lane + (m << 6);
                u16x8 kv = rowp[c];
                float4 ua = ut4[2 * c], ub = ut4[2 * c + 1];
                s += b2f(kv[0]) * ua.x + b2f(kv[1]) * ua.y + b2f(kv[2]) * ua.z + b2f(kv[3]) * ua.w;
                s += b2f(kv[4]) * ub.x + b2f(kv[5]) * ub.y + b2f(kv[6]) * ub.z + b2f(kv[7]) * ub.w;
            }
            s = wsum(s);
            if (lane == 0) {
                float Ebj = Eb[j];
                if (absorb) { Ebj *= vv[j]; Eb[j] = Ebj; }  // lazy beta absorb from it-1
                const float tj = s * su;
                const float vj = AMARG / (Ebj * tj + EPSS);
                vv[j] = vj;
                vt[j] = Ebj * vj;
                if (vj > TAUV) atomicOr(flags + fcur, 1);
            }
        }
        grid.sync();

        // P2: per row i:  s_i = sum_j K0[i][j]*vt[j];  u_i = a/(Ea_i*s_i + eps)
        for (int i = gw; i < NN; i += nw) {
            const u16x8* rowp = (const u16x8*)(K0 + (size_t)i * NN);
            float s = 0.f;
#pragma unroll
            for (int m = 0; m < 8; ++m) {
                const int c = lane + (m << 6);
                u16x8 kv = rowp[c];
                float4 va = vt4[2 * c], vb = vt4[2 * c + 1];
                s += b2f(kv[0]) * va.x + b2f(kv[1]) * va.y + b2f(kv[2]) * va.z + b2f(kv[3]) * va.w;
                s += b2f(kv[4]) * vb.x + b2f(kv[5]) * vb.y + b2f(kv[6]) * vb.z + b2f(kv[7]) * vb.w;
            }
            s = wsum(s);
            if (lane == 0) {
                float Eai = Ea[i];
                if (absorb) { Eai *= uu[i]; Ea[i] = Eai; }  // lazy alpha absorb from it-1
                const float ui = AMARG / (Eai * s + EPSS);
                uu[i] = ui;
                ut[i] = Eai * ui;
                if (ui > TAUV) atomicOr(flags + fcur, 1);
            }
        }
        grid.sync();
    }

    // ---------------- F: loss = scale * sum_ij K0*M*ut_i*vt_j,  M = -eps*log(K0) ----
    const bool absorbF = (*(volatile int*)(flags + (NITER + 2) % 3)) != 0;
    const float scale = absorbF ? (AMARG * AMARG) : 1.f;  // pending final absorb: ut*=a, vt*=b
    float lsum = 0.f;
    for (int i = gw; i < NN; i += nw) {
        const u16x8* rowp = (const u16x8*)(K0 + (size_t)i * NN);
        float s = 0.f;
#pragma unroll 2
        for (int m = 0; m < 8; ++m) {
            const int c = lane + (m << 6);
            u16x8 kv = rowp[c];
            float4 va = vt4[2 * c], vb = vt4[2 * c + 1];
            float k0;
            k0 = b2f(kv[0]); s += k0 * __logf(k0) * va.x;
            k0 = b2f(kv[1]); s += k0 * __logf(k0) * va.y;
            k0 = b2f(kv[2]); s += k0 * __logf(k0) * va.z;
            k0 = b2f(kv[3]); s += k0 * __logf(k0) * va.w;
            k0 = b2f(kv[4]); s += k0 * __logf(k0) * vb.x;
            k0 = b2f(kv[5]); s += k0 * __logf(k0) * vb.y;
            k0 = b2f(kv[6]); s += k0 * __logf(k0) * vb.z;
            k0 = b2f(kv[7]); s += k0 * __logf(k0) * vb.w;
        }
        s = wsum(s);
        if (lane == 0) lsum += (-REGE) * s * ut[i];
    }
    if (lane == 0) red[wid] = lsum;
    __syncthreads();
    if (tid == 0) {
        float tot = (red[0] + red[1]) + (red[2] + red[3]);
        atomicAdd(out, tot * scale);
    }
}

extern "C" void kernel_launch(void* const* d_in, const int* in_sizes, int n_in,
                              void* d_out, int out_size, void* d_ws, size_t ws_size,
                              hipStream_t stream) {
    const float* x = (const float*)d_in[0];
    const float* y = (const float*)d_in[1];
    float* out = (float*)d_out;
    char* ws = (char*)d_ws;

    // ws layout: K0 bf16 [4096x4096] (32MB) | K0T bf16 (32MB) | 8 fp32 vectors of 4096 | 3 int flags
    u16* K0  = (u16*)(ws);
    u16* K0T = (u16*)(ws + 33554432ull);
    float* fb = (float*)(ws + 67108864ull);
    float* xsq = fb + 0 * 4096;
    float* ysq = fb + 1 * 4096;
    float* Ea  = fb + 2 * 4096;
    float* Eb  = fb + 3 * 4096;
    float* uu  = fb + 4 * 4096;
    float* vv  = fb + 5 * 4096;
    float* ut  = fb + 6 * 4096;
    float* vt  = fb + 7 * 4096;
    int* flags = (int*)(fb + 8 * 4096);

    void* args[] = {&x, &y, &out, &K0, &K0T, &xsq, &ysq, &Ea, &Eb, &uu, &vv, &ut, &vt, &flags};

    // co-residency-safe grid: query occupancy, cap at 4 blocks/CU (1024 blocks)
    int nb = 0;
    hipOccupancyMaxActiveBlocksPerMultiprocessor(&nb, sinkhorn_all, 256, 0);
    if (nb < 1) nb = 1;
    if (nb > 4) nb = 4;
    dim3 block(256);
    dim3 grid(nb * 256);
    hipError_t err = hipLaunchCooperativeKernel((void*)sinkhorn_all, grid, block,
                                                (void**)args, 0, stream);
    if (err != hipSuccess) {
        (void)hipLaunchCooperativeKernel((void*)sinkhorn_all, dim3(256), block,
                                         (void**)args, 0, stream);
    }
}

// Round 2
// 3633.808 us; speedup vs baseline: 1.9493x; 1.9493x over previous
//
#include <hip/hip_runtime.h>
#include <hip/hip_cooperative_groups.h>

namespace cg = cooperative_groups;

typedef unsigned short u16;
typedef __attribute__((ext_vector_type(8))) u16 u16x8;
typedef __attribute__((ext_vector_type(4))) u16 u16x4;

#define NN 4096
#define NITER 50
#define REGE 10.0f
#define TAUV 1000.0f
#define AMARG (1.0f / 4096.0f)
#define EPSS 1e-16f

__device__ __forceinline__ float b2f(u16 h) { return __uint_as_float(((unsigned)h) << 16); }
__device__ __forceinline__ u16 f2b(float f) {
    unsigned x = __float_as_uint(f);
    return (u16)((x + 0x7FFFu + ((x >> 16) & 1u)) >> 16);
}
__device__ __forceinline__ float wsum(float v) {
#pragma unroll
    for (int off = 32; off; off >>= 1) v += __shfl_xor(v, off, 64);
    return v;
}
// Agent-scope (device-coherent, L1/L2-bypassing) accesses for cross-block data.
// Relaxed => no buffer_inv/buffer_wbl2 cache maintenance => K0/K0T stay L2-resident.
__device__ __forceinline__ float agent_ldf(const float* p) {
    return __hip_atomic_load(p, __ATOMIC_RELAXED, __HIP_MEMORY_SCOPE_AGENT);
}
__device__ __forceinline__ void agent_stf(float* p, float v) {
    __hip_atomic_store(p, v, __ATOMIC_RELAXED, __HIP_MEMORY_SCOPE_AGENT);
}
__device__ __forceinline__ int agent_ldi(const int* p) {
    return __hip_atomic_load(p, __ATOMIC_RELAXED, __HIP_MEMORY_SCOPE_AGENT);
}
__device__ __forceinline__ void agent_sti(int* p, int v) {
    __hip_atomic_store(p, v, __ATOMIC_RELAXED, __HIP_MEMORY_SCOPE_AGENT);
}

// Lightweight grid barrier: RELEASE arrival (drains stores, wbl2 writeback only —
// no invalidate), RELAXED spin (no invalidate). Cross-phase data is agent-scope
// (sc1) only, so no acquire-invalidate is ever needed in the hot loop.
__device__ __forceinline__ void gbar(int* cnt, int target, int tid) {
    __syncthreads();   // all waves done; compiler drains vmcnt before s_barrier
    if (tid == 0) {
        (void)__hip_atomic_fetch_add(cnt, 1, __ATOMIC_RELEASE, __HIP_MEMORY_SCOPE_AGENT);
        while (__hip_atomic_load(cnt, __ATOMIC_RELAXED, __HIP_MEMORY_SCOPE_AGENT) < target)
            __builtin_amdgcn_s_sleep(2);
    }
    __syncthreads();
}

// One half-iteration: out_j-update for rows [row0,row0+rpb) of Kmat (row-major,
// bf16). Each wave computes a 1024-column partial dot; per-block finalize.
// invec staged: coalesced agent loads -> padded LDS (bank-conflict-free) -> regs.
__device__ __forceinline__ void phase(
    const u16* __restrict__ Kmat, const float* __restrict__ invec,
    float* __restrict__ Evec, float* __restrict__ auxvec, float* __restrict__ outvec,
    int* __restrict__ flagp, bool absorb, float su,
    float (*psh)[4], float* stage,
    int row0, int rpb, int tid, int lane, int wid) {
    // stage invec (4096 floats) into LDS, padded +1 float per 16 (bank spread)
    float sv[16];
#pragma unroll
    for (int m = 0; m < 16; ++m) sv[m] = agent_ldf(invec + (m << 8) + tid);
#pragma unroll
    for (int m = 0; m < 16; ++m) {
        const int g = (m << 8) + tid;
        stage[g + (g >> 4)] = sv[m];
    }
    __syncthreads();
    float uf[16];
    const int base = 1088 * wid + 17 * lane;   // padded index of c0
#pragma unroll
    for (int k = 0; k < 16; ++k) uf[k] = stage[base + k];   // banks (17l+k)%32: conflict-free
    const int c0 = (wid << 10) + (lane << 4);

    for (int rb = 0; rb < rpb; rb += 8) {
        float part[8];
#pragma unroll
        for (int r = 0; r < 8; ++r) {
            const int j = row0 + rb + r;
            const u16x8* kp = (const u16x8*)(Kmat + (size_t)j * NN + c0);
            u16x8 ka = kp[0], kb = kp[1];
            float s = 0.f;
#pragma unroll
            for (int k = 0; k < 8; ++k) s = __fmaf_rn(b2f(ka[k]), uf[k], s);
#pragma unroll
            for (int k = 0; k < 8; ++k) s = __fmaf_rn(b2f(kb[k]), uf[8 + k], s);
            part[r] = s;
        }
#pragma unroll
        for (int r = 0; r < 8; ++r) part[r] = wsum(part[r]);
        if (lane == 0) {
#pragma unroll
            for (int r = 0; r < 8; ++r) psh[r][wid] = part[r];
        }
        __syncthreads();
        if (tid < 8) {   // wave-0 lanes 0..7 finalize the 8 rows (block-private state)
            const int j = row0 + rb + tid;
            float t = (psh[tid][0] + psh[tid][1]) + (psh[tid][2] + psh[tid][3]);
            float E = Evec[j];
            if (absorb) { E *= auxvec[j]; Evec[j] = E; }
            const float w = AMARG / (E * (t * su) + EPSS);
            auxvec[j] = w;
            agent_stf(outvec + j, E * w);
            if (w > TAUV)
                (void)__hip_atomic_fetch_or(flagp, 1, __ATOMIC_RELAXED, __HIP_MEMORY_SCOPE_AGENT);
        }
        __syncthreads();   // psh reuse guard
    }
}

__global__ __launch_bounds__(256, 2) void sinkhorn_all(
    const float* __restrict__ x, const float* __restrict__ y, float* __restrict__ out,
    u16* __restrict__ K0, u16* __restrict__ K0T,
    float* __restrict__ xsq, float* __restrict__ ysq,
    float* __restrict__ Ea, float* __restrict__ Eb,
    float* __restrict__ uu, float* __restrict__ vv,
    float* __restrict__ ut, float* __restrict__ vt,
    int* __restrict__ flags) {
    cg::grid_group grid = cg::this_grid();
    union ShMem {
        struct { float xs[64][65]; float ys[64][65]; } s1;   // K-build tiles (setup only)
        float stage[4096 + 256];                              // padded vector stage (iterations)
    };
    __shared__ ShMem sh;
    __shared__ float psh[8][4];
    __shared__ int absorb_sh;

    const int tid  = threadIdx.x;
    const int lane = tid & 63;
    const int wid  = tid >> 6;
    const int nbl  = gridDim.x;
    const int gw   = blockIdx.x * 4 + wid;
    const int nw   = nbl * 4;
    const int rpb  = NN / nbl;            // rows per block (8 at 512 blocks)
    const int row0 = blockIdx.x * rpb;
    int* cnt = flags + 3;                 // barrier counter

    // ---------------- S0: row squared norms + state init ----------------
    for (int r = gw; r < 2 * NN; r += nw) {
        const float* src = (r < NN) ? (x + (size_t)r * 64) : (y + (size_t)(r - NN) * 64);
        float t = src[lane];
        float s = wsum(t * t);
        if (lane == 0) { if (r < NN) xsq[r] = s; else ysq[r - NN] = s; }
    }
    for (int i = blockIdx.x * 256 + tid; i < NN; i += nbl * 256) {
        Ea[i] = 1.f; Eb[i] = 1.f; uu[i] = AMARG; vv[i] = AMARG;
        ut[i] = AMARG; vt[i] = AMARG;
    }
    if (blockIdx.x == 0) {
        if (tid < 4) flags[tid] = 0;      // 3 absorb flags + barrier counter
        if (tid == 0) out[0] = 0.f;
    }
    grid.sync();   // full fence: flush/inv once (also clears stale poison lines)

    // ---------------- S1: K0 = exp(-M/eps) bf16, plus K0T ----------------
    {
        const int tx = tid & 15, ty = tid >> 4;
        for (int tile = blockIdx.x; tile < 64 * 64; tile += nbl) {
            const int i0 = (tile >> 6) << 6;
            const int j0 = (tile & 63) << 6;
            __syncthreads();
            for (int e = tid; e < 4096; e += 256) {
                const int r = e >> 6, c = e & 63;
                sh.s1.xs[r][c] = x[(size_t)(i0 + r) * 64 + c];
                sh.s1.ys[r][c] = y[(size_t)(j0 + r) * 64 + c];
            }
            __syncthreads();
            float acc[4][4] = {};
#pragma unroll
            for (int k = 0; k < 64; ++k) {
                float xv[4], yv[4];
#pragma unroll
                for (int r = 0; r < 4; ++r) xv[r] = sh.s1.xs[ty * 4 + r][k];
#pragma unroll
                for (int c = 0; c < 4; ++c) yv[c] = sh.s1.ys[tx * 4 + c][k];
#pragma unroll
                for (int r = 0; r < 4; ++r)
#pragma unroll
                    for (int c = 0; c < 4; ++c)
                        acc[r][c] = __fmaf_rn(xv[r], yv[c], acc[r][c]);
            }
            u16 kb[4][4];
#pragma unroll
            for (int r = 0; r < 4; ++r) {
                const float xq = xsq[i0 + ty * 4 + r];
#pragma unroll
                for (int c = 0; c < 4; ++c) {
                    const float m = xq + ysq[j0 + tx * 4 + c] - 2.f * acc[r][c];
                    kb[r][c] = f2b(__expf(-m * (1.0f / REGE)));
                }
            }
#pragma unroll
            for (int r = 0; r < 4; ++r) {
                u16x4 pk = {kb[r][0], kb[r][1], kb[r][2], kb[r][3]};
                *(u16x4*)(K0 + (size_t)(i0 + ty * 4 + r) * NN + j0 + tx * 4) = pk;
            }
#pragma unroll
            for (int c = 0; c < 4; ++c) {
                u16x4 pk = {kb[0][c], kb[1][c], kb[2][c], kb[3][c]};
                *(u16x4*)(K0T + (size_t)(j0 + tx * 4 + c) * NN + i0 + ty * 4) = pk;
            }
        }
    }
    grid.sync();   // full fence: K0/K0T now globally visible; read-only hereafter

    // ---------------- 50 Sinkhorn iterations (custom barriers only) ------
    int ep = 0;
    for (int it = 0; it < NITER; ++it) {
        const int fprev = (it + 2) % 3;
        const int fcur  = it % 3;
        const int fnext = (it + 1) % 3;
        if (tid == 0) {
            absorb_sh = agent_ldi(flags + fprev);
            if (blockIdx.x == 0) agent_sti(flags + fnext, 0);
        }
        __syncthreads();
        const bool absorb = absorb_sh != 0;
        const float su = absorb ? AMARG : 1.f;

        // P1: t = K0T~ut -> v, vt   (lazy beta absorb from it-1)
        phase(K0T, ut, Eb, vv, vt, flags + fcur, absorb, su,
              psh, sh.stage, row0, rpb, tid, lane, wid);
        ++ep; gbar(cnt, nbl * ep, tid);

        // P2: s = K0 vt -> u, ut    (lazy alpha absorb from it-1)
        phase(K0, vt, Ea, uu, ut, flags + fcur, absorb, 1.f,
              psh, sh.stage, row0, rpb, tid, lane, wid);
        ++ep; gbar(cnt, nbl * ep, tid);
    }

    // ---------------- F: loss = scale * sum_ij K0 * (-eps log K0) * ut_i * vt_j
    if (tid == 0) absorb_sh = agent_ldi(flags + (NITER + 2) % 3);
    __syncthreads();
    const float scale = absorb_sh ? (AMARG * AMARG) : 1.f;

    {   // stage vt
        float sv[16];
#pragma unroll
        for (int m = 0; m < 16; ++m) sv[m] = agent_ldf(vt + (m << 8) + tid);
        __syncthreads();   // stage buffer free (prior phase consumers done in-block)
#pragma unroll
        for (int m = 0; m < 16; ++m) {
            const int g = (m << 8) + tid;
            sh.stage[g + (g >> 4)] = sv[m];
        }
    }
    __syncthreads();
    float vf[16];
    const int base = 1088 * wid + 17 * lane;
#pragma unroll
    for (int k = 0; k < 16; ++k) vf[k] = sh.stage[base + k];
    const int c0 = (wid << 10) + (lane << 4);

    float bacc = 0.f;
    for (int rb = 0; rb < rpb; rb += 8) {
        float part[8];
#pragma unroll
        for (int r = 0; r < 8; ++r) {
            const int i = row0 + rb + r;
            const u16x8* kp = (const u16x8*)(K0 + (size_t)i * NN + c0);
            u16x8 ka = kp[0], kb2 = kp[1];
            float s = 0.f;
#pragma unroll
            for (int k = 0; k < 8; ++k) {
                const float k0v = b2f(ka[k]);
                s = __fmaf_rn(k0v * __logf(k0v), vf[k], s);
            }
#pragma unroll
            for (int k = 0; k < 8; ++k) {
                const float k0v = b2f(kb2[k]);
                s = __fmaf_rn(k0v * __logf(k0v), vf[8 + k], s);
            }
            part[r] = s;
        }
#pragma unroll
        for (int r = 0; r < 8; ++r) part[r] = wsum(part[r]);
        if (lane == 0) {
#pragma unroll
            for (int r = 0; r < 8; ++r) psh[r][wid] = part[r];
        }
        __syncthreads();
        if (tid < 8) {
            const int i = row0 + rb + tid;
            const float rs = (psh[tid][0] + psh[tid][1]) + (psh[tid][2] + psh[tid][3]);
            bacc += rs * agent_ldf(ut + i);
        }
        __syncthreads();
    }
    bacc += __shfl_xor(bacc, 1, 64);
    bacc += __shfl_xor(bacc, 2, 64);
    bacc += __shfl_xor(bacc, 4, 64);
    if (tid == 0) atomicAdd(out, bacc * (-REGE) * scale);
}

extern "C" void kernel_launch(void* const* d_in, const int* in_sizes, int n_in,
                              void* d_out, int out_size, void* d_ws, size_t ws_size,
                              hipStream_t stream) {
    const float* x = (const float*)d_in[0];
    const float* y = (const float*)d_in[1];
    float* out = (float*)d_out;
    char* ws = (char*)d_ws;

    // ws: K0 bf16 32MB | K0T bf16 32MB | 8 fp32 vectors of 4096 | 4 ints (flags+barrier)
    u16* K0  = (u16*)(ws);
    u16* K0T = (u16*)(ws + 33554432ull);
    float* fb = (float*)(ws + 67108864ull);
    float* xsq = fb + 0 * 4096;
    float* ysq = fb + 1 * 4096;
    float* Ea  = fb + 2 * 4096;
    float* Eb  = fb + 3 * 4096;
    float* uu  = fb + 4 * 4096;
    float* vv  = fb + 5 * 4096;
    float* ut  = fb + 6 * 4096;
    float* vt  = fb + 7 * 4096;
    int* flags = (int*)(fb + 8 * 4096);

    void* args[] = {&x, &y, &out, &K0, &K0T, &xsq, &ysq, &Ea, &Eb, &uu, &vv, &ut, &vt, &flags};

    // 512 blocks = 2/CU (grid-size-agnostic kernel; fallback 256 = 1/CU)
    hipError_t err = hipLaunchCooperativeKernel((void*)sinkhorn_all, dim3(512), dim3(256),
                                                (void**)args, 0, stream);
    if (err != hipSuccess) {
        (void)hipLaunchCooperativeKernel((void*)sinkhorn_all, dim3(256), dim3(256),
                                         (void**)args, 0, stream);
    }
}

// Round 3
// 1827.805 us; speedup vs baseline: 3.8754x; 1.9881x over previous
//
#include <hip/hip_runtime.h>
#include <hip/hip_cooperative_groups.h>

namespace cg = cooperative_groups;

typedef unsigned short u16;
typedef __attribute__((ext_vector_type(8))) u16 u16x8;
typedef __attribute__((ext_vector_type(4))) u16 u16x4;

#define NN 4096
#define NITER 50
#define REGE 10.0f
#define TAUV 1000.0f
#define AMARG (1.0f / 4096.0f)
#define EPSS 1e-16f
#define NG 32   // barrier arrival groups (one cache line each)

__device__ __forceinline__ float b2f(u16 h) { return __uint_as_float(((unsigned)h) << 16); }
__device__ __forceinline__ u16 f2b(float f) {
    unsigned x = __float_as_uint(f);
    return (u16)((x + 0x7FFFu + ((x >> 16) & 1u)) >> 16);
}
__device__ __forceinline__ float wsum(float v) {
#pragma unroll
    for (int off = 32; off; off >>= 1) v += __shfl_xor(v, off, 64);
    return v;
}
// Agent-scope (sc0 sc1: L1/L2-bypassing, L3-coherent) ops for cross-block data.
// RELAXED => no buffer_inv / buffer_wbl2 => K0/K0T stay L2-resident.
__device__ __forceinline__ float agent_ldf(const float* p) {
    return __hip_atomic_load(p, __ATOMIC_RELAXED, __HIP_MEMORY_SCOPE_AGENT);
}
__device__ __forceinline__ void agent_stf(float* p, float v) {
    __hip_atomic_store(p, v, __ATOMIC_RELAXED, __HIP_MEMORY_SCOPE_AGENT);
}
__device__ __forceinline__ int agent_ldi(const int* p) {
    return __hip_atomic_load(p, __ATOMIC_RELAXED, __HIP_MEMORY_SCOPE_AGENT);
}
__device__ __forceinline__ void agent_sti(int* p, int v) {
    __hip_atomic_store(p, v, __ATOMIC_RELAXED, __HIP_MEMORY_SCOPE_AGENT);
}

// Two-level grid barrier. Arrival: relaxed same-line RMW per group (<=32/line),
// preceded by explicit vmcnt drain (all cross-phase data is sc1 => visible at L3
// once vmcnt==0; no cache maintenance needed). Group-last bumps root; global-last
// broadcasts epoch to per-group release lines; everyone else spins read-only on
// its own group line.
__device__ __forceinline__ void gbar(int* arr, int* root, int* rel,
                                     int g, int gs, int ep, int tid) {
    __syncthreads();   // per-wave vmcnt drained by compiler before s_barrier
    if (tid == 0) {
        asm volatile("s_waitcnt vmcnt(0)" ::: "memory");
        const int old = __hip_atomic_fetch_add(arr + g * 32, 1,
                                               __ATOMIC_RELAXED, __HIP_MEMORY_SCOPE_AGENT);
        if (old == gs * ep - 1) {
            const int r = __hip_atomic_fetch_add(root, 1,
                                                 __ATOMIC_RELAXED, __HIP_MEMORY_SCOPE_AGENT);
            if (r == NG * ep - 1) {
#pragma unroll
                for (int i = 0; i < NG; ++i) agent_sti(rel + i * 32, ep);
            } else {
                while (agent_ldi(rel + g * 32) < ep) __builtin_amdgcn_s_sleep(1);
            }
        } else {
            while (agent_ldi(rel + g * 32) < ep) __builtin_amdgcn_s_sleep(1);
        }
    }
    __syncthreads();
}

// Half-iteration: rows [row0,row0+rpb) of Kmat (bf16 row-major). Wave w covers
// cols [w*1024,(w+1)*1024); lane holds 16 cols. Quarter sums combined via psh.
__device__ __forceinline__ void phase(
    const u16* __restrict__ Kmat, const float* __restrict__ invec,
    float* __restrict__ Evec, float* __restrict__ auxvec, float* __restrict__ outvec,
    int* __restrict__ flagp, bool absorb, float su,
    float (*psh)[4], int row0, int rpb, int tid, int lane, int wid) {
    const int c0 = (wid << 10) + (lane << 4);
    float uf[16];
#pragma unroll
    for (int k = 0; k < 16; ++k) uf[k] = agent_ldf(invec + c0 + k);

    for (int rb = 0; rb < rpb; rb += 4) {
        float part[4];
#pragma unroll
        for (int r = 0; r < 4; ++r) {
            const int j = row0 + rb + r;
            const u16x8* kp = (const u16x8*)(Kmat + (size_t)j * NN + c0);
            u16x8 ka = kp[0], kb = kp[1];
            float s = 0.f;
#pragma unroll
            for (int k = 0; k < 8; ++k) s = __fmaf_rn(b2f(ka[k]), uf[k], s);
#pragma unroll
            for (int k = 0; k < 8; ++k) s = __fmaf_rn(b2f(kb[k]), uf[8 + k], s);
            part[r] = s;
        }
#pragma unroll
        for (int r = 0; r < 4; ++r) part[r] = wsum(part[r]);
        if (lane == 0) {
#pragma unroll
            for (int r = 0; r < 4; ++r) psh[r][wid] = part[r];
        }
        __syncthreads();
        if (tid < 4) {
            const int j = row0 + rb + tid;
            const float t = (psh[tid][0] + psh[tid][1]) + (psh[tid][2] + psh[tid][3]);
            float E = Evec[j];
            if (absorb) { E *= auxvec[j]; Evec[j] = E; }
            const float w = AMARG / (E * (t * su) + EPSS);
            auxvec[j] = w;
            agent_stf(outvec + j, E * w);
            if (w > TAUV)
                (void)__hip_atomic_fetch_or(flagp, 1, __ATOMIC_RELAXED, __HIP_MEMORY_SCOPE_AGENT);
        }
        __syncthreads();   // psh reuse guard (multi-chunk fallback grids)
    }
}

__global__ __launch_bounds__(256, 4) void sinkhorn_all(
    const float* __restrict__ x, const float* __restrict__ y, float* __restrict__ out,
    u16* __restrict__ K0, u16* __restrict__ K0T,
    float* __restrict__ xsq, float* __restrict__ ysq,
    float* __restrict__ Ea, float* __restrict__ Eb,
    float* __restrict__ uu, float* __restrict__ vv,
    float* __restrict__ ut, float* __restrict__ vt,
    int* __restrict__ bar) {
    cg::grid_group grid = cg::this_grid();
    __shared__ float xs[64][65];
    __shared__ float ys[64][65];
    __shared__ float psh[4][4];
    __shared__ int absorb_sh;

    const int tid  = threadIdx.x;
    const int lane = tid & 63;
    const int wid  = tid >> 6;
    const int nbl  = gridDim.x;
    const int gw   = blockIdx.x * 4 + wid;
    const int nw   = nbl * 4;
    const int rpb  = NN / nbl;              // 4 at 1024 blocks
    const int row0 = blockIdx.x * rpb;
    const int gs   = nbl / NG;              // blocks per barrier group
    const int g    = blockIdx.x / gs;

    int* flags = bar;          // [0..2] absorb flags
    int* arr   = bar + 32;     // NG lines
    int* root  = bar + 32 + NG * 32;
    int* rel   = bar + 64 + NG * 32;

    // ---------------- S0: row norms + state init ----------------
    for (int r = gw; r < 2 * NN; r += nw) {
        const float* src = (r < NN) ? (x + (size_t)r * 64) : (y + (size_t)(r - NN) * 64);
        float t = src[lane];
        float s = wsum(t * t);
        if (lane == 0) { if (r < NN) xsq[r] = s; else ysq[r - NN] = s; }
    }
    if (tid < rpb) {           // block-local rows: state stays in this XCD's L2
        const int i = row0 + tid;
        Ea[i] = 1.f; Eb[i] = 1.f; uu[i] = AMARG; vv[i] = AMARG;
        agent_stf(ut + i, AMARG); agent_stf(vt + i, AMARG);
    }
    if (blockIdx.x == 0) {
        if (tid < NG) { arr[tid * 32] = 0; rel[tid * 32] = 0; }
        if (tid == 0) { *root = 0; flags[0] = 0; flags[1] = 0; flags[2] = 0; out[0] = 0.f; }
    }
    grid.sync();   // full fence (flushes init, clears poison lines)

    // ---------------- S1: K0 = exp(-M/eps) bf16, plus K0T ----------------
    {
        const int tx = tid & 15, ty = tid >> 4;
        for (int tile = blockIdx.x; tile < 64 * 64; tile += nbl) {
            const int i0 = (tile >> 6) << 6;
            const int j0 = (tile & 63) << 6;
            __syncthreads();
            for (int e = tid; e < 4096; e += 256) {
                const int r = e >> 6, c = e & 63;
                xs[r][c] = x[(size_t)(i0 + r) * 64 + c];
                ys[r][c] = y[(size_t)(j0 + r) * 64 + c];
            }
            __syncthreads();
            float acc[4][4] = {};
#pragma unroll
            for (int k = 0; k < 64; ++k) {
                float xv[4], yv[4];
#pragma unroll
                for (int r = 0; r < 4; ++r) xv[r] = xs[ty * 4 + r][k];
#pragma unroll
                for (int c = 0; c < 4; ++c) yv[c] = ys[tx * 4 + c][k];
#pragma unroll
                for (int r = 0; r < 4; ++r)
#pragma unroll
                    for (int c = 0; c < 4; ++c)
                        acc[r][c] = __fmaf_rn(xv[r], yv[c], acc[r][c]);
            }
            u16 kb[4][4];
#pragma unroll
            for (int r = 0; r < 4; ++r) {
                const float xq = xsq[i0 + ty * 4 + r];
#pragma unroll
                for (int c = 0; c < 4; ++c) {
                    const float m = xq + ysq[j0 + tx * 4 + c] - 2.f * acc[r][c];
                    kb[r][c] = f2b(__expf(-m * (1.0f / REGE)));
                }
            }
#pragma unroll
            for (int r = 0; r < 4; ++r) {
                u16x4 pk = {kb[r][0], kb[r][1], kb[r][2], kb[r][3]};
                *(u16x4*)(K0 + (size_t)(i0 + ty * 4 + r) * NN + j0 + tx * 4) = pk;
            }
#pragma unroll
            for (int c = 0; c < 4; ++c) {
                u16x4 pk = {kb[0][c], kb[1][c], kb[2][c], kb[3][c]};
                *(u16x4*)(K0T + (size_t)(j0 + tx * 4 + c) * NN + i0 + ty * 4) = pk;
            }
        }
    }
    grid.sync();   // full fence: K0/K0T visible everywhere; read-only hereafter

    // ---------------- 50 Sinkhorn iterations ----------------
    int ep = 0;
    for (int it = 0; it < NITER; ++it) {
        const int fprev = (it + 2) % 3;
        const int fcur  = it % 3;
        const int fnext = (it + 1) % 3;
        if (tid == 0) {
            absorb_sh = agent_ldi(flags + fprev);
            if (blockIdx.x == 0) agent_sti(flags + fnext, 0);
        }
        __syncthreads();
        const bool absorb = absorb_sh != 0;
        const float su = absorb ? AMARG : 1.f;

        phase(K0T, ut, Eb, vv, vt, flags + fcur, absorb, su,
              psh, row0, rpb, tid, lane, wid);
        ++ep; gbar(arr, root, rel, g, gs, ep, tid);

        phase(K0, vt, Ea, uu, ut, flags + fcur, absorb, 1.f,
              psh, row0, rpb, tid, lane, wid);
        ++ep; gbar(arr, root, rel, g, gs, ep, tid);
    }

    // ---------------- F: loss = scale * sum_ij K0*(-eps log K0)*ut_i*vt_j ----
    if (tid == 0) absorb_sh = agent_ldi(flags + (NITER + 2) % 3);
    __syncthreads();
    const float scale = absorb_sh ? (AMARG * AMARG) : 1.f;

    const int c0 = (wid << 10) + (lane << 4);
    float vf[16];
#pragma unroll
    for (int k = 0; k < 16; ++k) vf[k] = agent_ldf(vt + c0 + k);

    float bacc = 0.f;
    for (int rb = 0; rb < rpb; rb += 4) {
        float part[4];
#pragma unroll
        for (int r = 0; r < 4; ++r) {
            const int i = row0 + rb + r;
            const u16x8* kp = (const u16x8*)(K0 + (size_t)i * NN + c0);
            u16x8 ka = kp[0], kb2 = kp[1];
            float s = 0.f;
#pragma unroll
            for (int k = 0; k < 8; ++k) {
                const float k0v = b2f(ka[k]);
                s = __fmaf_rn(k0v * __logf(k0v), vf[k], s);
            }
#pragma unroll
            for (int k = 0; k < 8; ++k) {
                const float k0v = b2f(kb2[k]);
                s = __fmaf_rn(k0v * __logf(k0v), vf[8 + k], s);
            }
            part[r] = s;
        }
#pragma unroll
        for (int r = 0; r < 4; ++r) part[r] = wsum(part[r]);
        if (lane == 0) {
#pragma unroll
            for (int r = 0; r < 4; ++r) psh[r][wid] = part[r];
        }
        __syncthreads();
        if (tid < 4) {
            const int i = row0 + rb + tid;
            const float rs = (psh[tid][0] + psh[tid][1]) + (psh[tid][2] + psh[tid][3]);
            bacc += rs * agent_ldf(ut + i);
        }
        __syncthreads();
    }
    bacc += __shfl_xor(bacc, 1, 64);
    bacc += __shfl_xor(bacc, 2, 64);
    if (tid == 0) atomicAdd(out, bacc * (-REGE) * scale);
}

extern "C" void kernel_launch(void* const* d_in, const int* in_sizes, int n_in,
                              void* d_out, int out_size, void* d_ws, size_t ws_size,
                              hipStream_t stream) {
    const float* x = (const float*)d_in[0];
    const float* y = (const float*)d_in[1];
    float* out = (float*)d_out;
    char* ws = (char*)d_ws;

    // ws: K0 bf16 32MB | K0T bf16 32MB | 8 fp32 vectors of 4096 | barrier ints (~9KB)
    u16* K0  = (u16*)(ws);
    u16* K0T = (u16*)(ws + 33554432ull);
    float* fb = (float*)(ws + 67108864ull);
    float* xsq = fb + 0 * 4096;
    float* ysq = fb + 1 * 4096;
    float* Ea  = fb + 2 * 4096;
    float* Eb  = fb + 3 * 4096;
    float* uu  = fb + 4 * 4096;
    float* vv  = fb + 5 * 4096;
    float* ut  = fb + 6 * 4096;
    float* vt  = fb + 7 * 4096;
    int* bar   = (int*)(fb + 8 * 4096);

    void* args[] = {&x, &y, &out, &K0, &K0T, &xsq, &ysq, &Ea, &Eb, &uu, &vv, &ut, &vt, &bar};

    // 1024 blocks = 4/CU; grid-size-agnostic kernel (fallbacks 512/256)
    hipError_t err = hipLaunchCooperativeKernel((void*)sinkhorn_all, dim3(1024), dim3(256),
                                                (void**)args, 0, stream);
    if (err != hipSuccess)
        err = hipLaunchCooperativeKernel((void*)sinkhorn_all, dim3(512), dim3(256),
                                         (void**)args, 0, stream);
    if (err != hipSuccess)
        (void)hipLaunchCooperativeKernel((void*)sinkhorn_all, dim3(256), dim3(256),
                                         (void**)args, 0, stream);
}

// Round 4
// 1438.392 us; speedup vs baseline: 4.9246x; 1.2707x over previous
//
#include <hip/hip_runtime.h>
#include <hip/hip_cooperative_groups.h>

namespace cg = cooperative_groups;

typedef unsigned short u16;
typedef __attribute__((ext_vector_type(8))) u16 u16x8;
typedef __attribute__((ext_vector_type(2))) u16 u16x2;

#define NN 4096
#define NITER 50
#define REGE 10.0f
#define TAUV 1000.0f
#define AMARG (1.0f / 4096.0f)
#define EPSS 1e-16f
#define NB 256   // blocks (fixed: stripe arithmetic depends on it)
#define NG 16    // barrier groups
#define GS 16    // blocks per group

__device__ __forceinline__ float b2f(u16 h) { return __uint_as_float(((unsigned)h) << 16); }
__device__ __forceinline__ u16 f2b(float f) {
    unsigned x = __float_as_uint(f);
    return (u16)((x + 0x7FFFu + ((x >> 16) & 1u)) >> 16);
}
__device__ __forceinline__ float wsum(float v) {
#pragma unroll
    for (int off = 32; off; off >>= 1) v += __shfl_xor(v, off, 64);
    return v;
}
// Agent-scope (L1/L2-bypassing, L3-coherent) ops; RELAXED => no cache maintenance
// => K0 stripes stay L2-resident.
__device__ __forceinline__ float agent_ldf(const float* p) {
    return __hip_atomic_load(p, __ATOMIC_RELAXED, __HIP_MEMORY_SCOPE_AGENT);
}
__device__ __forceinline__ void agent_stf(float* p, float v) {
    __hip_atomic_store(p, v, __ATOMIC_RELAXED, __HIP_MEMORY_SCOPE_AGENT);
}
__device__ __forceinline__ int agent_ldi(const int* p) {
    return __hip_atomic_load(p, __ATOMIC_RELAXED, __HIP_MEMORY_SCOPE_AGENT);
}
__device__ __forceinline__ void agent_sti(int* p, int v) {
    __hip_atomic_store(p, v, __ATOMIC_RELAXED, __HIP_MEMORY_SCOPE_AGENT);
}

// Two-level grid barrier (verified R3). Arrival relies on __syncthreads'
// vmcnt(0) drain: all sc1 stores are L3-visible before the counter bump.
__device__ __forceinline__ void gbar(int* arr, int* root, int* rel,
                                     int g, int ep, int tid) {
    __syncthreads();
    if (tid == 0) {
        asm volatile("s_waitcnt vmcnt(0)" ::: "memory");
        const int old = __hip_atomic_fetch_add(arr + g * 32, 1,
                                               __ATOMIC_RELAXED, __HIP_MEMORY_SCOPE_AGENT);
        if (old == GS * ep - 1) {
            const int r = __hip_atomic_fetch_add(root, 1,
                                                 __ATOMIC_RELAXED, __HIP_MEMORY_SCOPE_AGENT);
            if (r == NG * ep - 1) {
#pragma unroll
                for (int i = 0; i < NG; ++i) agent_sti(rel + i * 32, ep);
            } else {
                while (agent_ldi(rel + g * 32) < ep) __builtin_amdgcn_s_sleep(1);
            }
        } else {
            while (agent_ldi(rel + g * 32) < ep) __builtin_amdgcn_s_sleep(1);
        }
    }
    __syncthreads();
}

__global__ __launch_bounds__(1024, 8) void sinkhorn_all(
    const float* __restrict__ x, const float* __restrict__ y, float* __restrict__ out,
    u16* __restrict__ K0,
    float* __restrict__ xsq, float* __restrict__ ysq,
    float* __restrict__ Ea, float* __restrict__ Eb,
    float* __restrict__ uu, float* __restrict__ vv,
    float* __restrict__ ut, float* __restrict__ vt,
    float* __restrict__ tpart, float* __restrict__ outpart,
    int* __restrict__ bar) {
    cg::grid_group grid = cg::this_grid();
    union Sh {
        struct { float xs[64][65]; float ys[64][65]; } bld;      // 33.3 KB (setup)
        struct {
            float vtl[NN + 256];        // padded vector stage (B / final)
            float psum[16][16][8];      // A: per-wave partials
            float psh[16];              // final: per-wave partials
            float uts[512];             // A: ut stripe slice
        } it;                           // 27.8 KB
    };
    __shared__ Sh sh;
    __shared__ int ibc;       // absorb-flag broadcast
    __shared__ int oldc_sh;   // last-finisher broadcast

    const int tid  = threadIdx.x;
    const int lane = tid & 63;
    const int wid  = tid >> 6;     // 0..15
    const int b    = blockIdx.x;
    const int c    = b & 7;        // stripe (rows [512c, 512c+512) of K0)
    const int l    = b >> 3;       // 0..31: chunk within stripe
    const int g    = b >> 4;       // barrier group

    int* flags = bar;                        // [0..2] absorb flags
    int* arr   = bar + 32;                   // NG lines
    int* root  = bar + 32 + NG * 32;
    int* rel   = bar + 64 + NG * 32;
    int* done  = bar + 64 + 2 * NG * 32;     // 32 chunk counters, 16-int spacing

    // ---------------- S0: row norms + state init ----------------
    for (int r = b * 16 + wid; r < 2 * NN; r += NB * 16) {
        const float* src = (r < NN) ? (x + (size_t)r * 64) : (y + (size_t)(r - NN) * 64);
        float t = src[lane];
        float s = wsum(t * t);
        if (lane == 0) { if (r < NN) xsq[r] = s; else ysq[r - NN] = s; }
    }
    {
        const int gt = b * 1024 + tid;
        if (gt < NN) {
            Ea[gt] = 1.f; Eb[gt] = 1.f; uu[gt] = AMARG; vv[gt] = AMARG;
            ut[gt] = AMARG; vt[gt] = AMARG;
        }
    }
    if (b == 0) {
        if (tid < NG) { arr[tid * 32] = 0; rel[tid * 32] = 0; }
        if (tid < 32) done[tid * 16] = 0;
        if (tid < 8) outpart[tid * 16] = 0.f;
        if (tid == 0) { *root = 0; flags[0] = 0; flags[1] = 0; flags[2] = 0; }
    }
    grid.sync();   // full fence: init visible, stale poison lines cleared

    // ---------------- S1: K0 = exp(-M/eps) bf16, stripe-aligned build ----
    {
        const int tx = tid & 31, ty = tid >> 5;   // 32x32 threads, 2x2 out each
        for (int q = 0; q < 16; ++q) {
            const int s = l * 16 + q;             // tile within stripe c
            const int i0 = (8 * c + (s >> 6)) * 64;
            const int j0 = (s & 63) * 64;
            __syncthreads();
            {
                const int row = tid >> 4, col4 = (tid & 15) * 4;
                *(float4*)&sh.bld.xs[row][col4] = *(const float4*)(x + (size_t)(i0 + row) * 64 + col4);
                *(float4*)&sh.bld.ys[row][col4] = *(const float4*)(y + (size_t)(j0 + row) * 64 + col4);
            }
            __syncthreads();
            float a00 = 0, a01 = 0, a10 = 0, a11 = 0;
#pragma unroll
            for (int k = 0; k < 64; ++k) {
                const float x0 = sh.bld.xs[ty * 2][k],     x1 = sh.bld.xs[ty * 2 + 1][k];
                const float y0 = sh.bld.ys[tx * 2][k],     y1 = sh.bld.ys[tx * 2 + 1][k];
                a00 = __fmaf_rn(x0, y0, a00); a01 = __fmaf_rn(x0, y1, a01);
                a10 = __fmaf_rn(x1, y0, a10); a11 = __fmaf_rn(x1, y1, a11);
            }
            const float xq0 = xsq[i0 + ty * 2], xq1 = xsq[i0 + ty * 2 + 1];
            const float yq0 = ysq[j0 + tx * 2], yq1 = ysq[j0 + tx * 2 + 1];
            u16x2 r0 = { f2b(__expf(-(xq0 + yq0 - 2.f * a00) * 0.1f)),
                         f2b(__expf(-(xq0 + yq1 - 2.f * a01) * 0.1f)) };
            u16x2 r1 = { f2b(__expf(-(xq1 + yq0 - 2.f * a10) * 0.1f)),
                         f2b(__expf(-(xq1 + yq1 - 2.f * a11) * 0.1f)) };
            *(u16x2*)(K0 + (size_t)(i0 + ty * 2) * NN + j0 + tx * 2) = r0;
            *(u16x2*)(K0 + (size_t)(i0 + ty * 2 + 1) * NN + j0 + tx * 2) = r1;
        }
    }
    grid.sync();   // K0 visible everywhere; read-only hereafter

    // ---------------- 50 Sinkhorn iterations ----------------
    int ep = 0;
    for (int it = 0; it < NITER; ++it) {
        const int fprev = (it + 2) % 3;
        const int fcur  = it % 3;
        const int fnext = (it + 1) % 3;
        if (tid == 0) {
            ibc = agent_ldi(flags + fprev);
            if (b == 0) agent_sti(flags + fnext, 0);
        }
        __syncthreads();
        const bool absorb = ibc != 0;
        const float su = absorb ? AMARG : 1.f;

        // ---- Phase A: t_j partials over stripe-c rows, j in [128l,128l+128) ----
        if (tid < 512) sh.it.uts[tid] = agent_ldf(ut + 512 * c + tid);
        __syncthreads();
        {
            const int jj8 = tid & 15, gg = tid >> 4;   // 8 j-cols, 8 i-rows each
            const u16* kbase = K0 + (size_t)(512 * c + 8 * gg) * NN + 128 * l + 8 * jj8;
            float acc[8] = {};
#pragma unroll
            for (int ii = 0; ii < 8; ++ii) {
                const float ui = sh.it.uts[8 * gg + ii];
                u16x8 kv = *(const u16x8*)(kbase + (size_t)ii * NN);
#pragma unroll
                for (int k = 0; k < 8; ++k) acc[k] = __fmaf_rn(b2f(kv[k]), ui, acc[k]);
            }
#pragma unroll
            for (int k = 0; k < 8; ++k) {   // sum the 4 g-subgroups within the wave
                acc[k] += __shfl_xor(acc[k], 16, 64);
                acc[k] += __shfl_xor(acc[k], 32, 64);
            }
            if ((lane >> 4) == 0) {
#pragma unroll
                for (int k = 0; k < 8; ++k) sh.it.psum[wid][lane][k] = acc[k];
            }
        }
        __syncthreads();
        if (tid < 128) {
            float tot = 0.f;
#pragma unroll
            for (int w = 0; w < 16; ++w) tot += sh.it.psum[w][tid >> 3][tid & 7];
            agent_stf(tpart + c * NN + 128 * l + tid, tot);   // coalesced sc1
        }
        __syncthreads();   // drains vmcnt: partial stores L3-visible
        if (tid == 0)
            oldc_sh = __hip_atomic_fetch_add(done + l * 16, 1,
                                             __ATOMIC_RELAXED, __HIP_MEMORY_SCOPE_AGENT);
        __syncthreads();
        if (oldc_sh == 8 * (it + 1) - 1 && tid < 128) {
            // last finisher for chunk l: all 8 stripe partials are visible
            const int j = 128 * l + tid;
            float tj = 0.f;
#pragma unroll
            for (int cc = 0; cc < 8; ++cc) tj += agent_ldf(tpart + cc * NN + j);
            float E = agent_ldf(Eb + j);
            if (absorb) { E *= agent_ldf(vv + j); agent_stf(Eb + j, E); }
            const float vj = AMARG / (E * (tj * su) + EPSS);
            agent_stf(vv + j, vj);
            agent_stf(vt + j, E * vj);
            if (vj > TAUV && agent_ldi(flags + fcur) == 0)
                (void)__hip_atomic_fetch_or(flags + fcur, 1,
                                            __ATOMIC_RELAXED, __HIP_MEMORY_SCOPE_AGENT);
        }
        ++ep; gbar(arr, root, rel, g, ep, tid);

        // ---- Phase B: full row-dots, rows i = 512c+16l+[0,16) ----
#pragma unroll
        for (int m = 0; m < 4; ++m) {
            const int j = m * 1024 + tid;
            sh.it.vtl[j + (j >> 4)] = agent_ldf(vt + j);
        }
        __syncthreads();
        {
            const int i = 512 * c + 16 * l + wid;
            const u16* krow = K0 + (size_t)i * NN;
            float s = 0.f;
#pragma unroll
            for (int seg = 0; seg < 4; ++seg) {
                const int j0 = seg * 1024 + lane * 16;
                const float* vp = &sh.it.vtl[j0 + (j0 >> 4)];
                u16x8 ka = *(const u16x8*)(krow + j0);
                u16x8 kb = *(const u16x8*)(krow + j0 + 8);
#pragma unroll
                for (int k = 0; k < 8; ++k) s = __fmaf_rn(b2f(ka[k]), vp[k], s);
#pragma unroll
                for (int k = 0; k < 8; ++k) s = __fmaf_rn(b2f(kb[k]), vp[8 + k], s);
            }
            s = wsum(s);
            if (lane == 0) {
                float E = Ea[i];                       // block-private, cached
                if (absorb) { E *= uu[i]; Ea[i] = E; }
                const float u2 = AMARG / (E * s + EPSS);
                uu[i] = u2;
                agent_stf(ut + i, E * u2);
                if (u2 > TAUV && agent_ldi(flags + fcur) == 0)
                    (void)__hip_atomic_fetch_or(flags + fcur, 1,
                                                __ATOMIC_RELAXED, __HIP_MEMORY_SCOPE_AGENT);
            }
        }
        ++ep; gbar(arr, root, rel, g, ep, tid);
    }

    // ---------------- F: loss = scale * sum_ij K0*(-eps log K0)*ut_i*vt_j ----
    if (tid == 0) ibc = agent_ldi(flags + (NITER + 2) % 3);
    __syncthreads();
    const float scale = ibc ? (AMARG * AMARG) : 1.f;

#pragma unroll
    for (int m = 0; m < 4; ++m) {
        const int j = m * 1024 + tid;
        sh.it.vtl[j + (j >> 4)] = agent_ldf(vt + j);
    }
    __syncthreads();
    {
        const int i = 512 * c + 16 * l + wid;
        const u16* krow = K0 + (size_t)i * NN;
        float s = 0.f;
#pragma unroll
        for (int seg = 0; seg < 4; ++seg) {
            const int j0 = seg * 1024 + lane * 16;
            const float* vp = &sh.it.vtl[j0 + (j0 >> 4)];
            u16x8 ka = *(const u16x8*)(krow + j0);
            u16x8 kb = *(const u16x8*)(krow + j0 + 8);
#pragma unroll
            for (int k = 0; k < 8; ++k) {
                const float kk = b2f(ka[k]);
                s = __fmaf_rn(kk * __logf(kk), vp[k], s);
            }
#pragma unroll
            for (int k = 0; k < 8; ++k) {
                const float kk = b2f(kb[k]);
                s = __fmaf_rn(kk * __logf(kk), vp[8 + k], s);
            }
        }
        s = wsum(s);
        if (lane == 0) sh.it.psh[wid] = s * agent_ldf(ut + i);
    }
    __syncthreads();
    if (tid == 0) {
        float bacc = 0.f;
#pragma unroll
        for (int w = 0; w < 16; ++w) bacc += sh.it.psh[w];
        (void)__hip_atomic_fetch_add(outpart + (b & 7) * 16, bacc,
                                     __ATOMIC_RELAXED, __HIP_MEMORY_SCOPE_AGENT);
    }
    ++ep; gbar(arr, root, rel, g, ep, tid);
    if (b == 0 && tid == 0) {
        float tot = 0.f;
#pragma unroll
        for (int k = 0; k < 8; ++k) tot += agent_ldf(outpart + k * 16);
        out[0] = tot * (-REGE) * scale;
    }
}

extern "C" void kernel_launch(void* const* d_in, const int* in_sizes, int n_in,
                              void* d_out, int out_size, void* d_ws, size_t ws_size,
                              hipStream_t stream) {
    const float* x = (const float*)d_in[0];
    const float* y = (const float*)d_in[1];
    float* out = (float*)d_out;
    char* ws = (char*)d_ws;

    // ws: K0 bf16 32MB | 8 fp32 vectors of 4096 | tpart[8][4096] | outpart | bar ints
    u16* K0 = (u16*)(ws);
    float* fb = (float*)(ws + 33554432ull);
    float* xsq = fb + 0 * 4096;
    float* ysq = fb + 1 * 4096;
    float* Ea  = fb + 2 * 4096;
    float* Eb  = fb + 3 * 4096;
    float* uu  = fb + 4 * 4096;
    float* vv  = fb + 5 * 4096;
    float* ut  = fb + 6 * 4096;
    float* vt  = fb + 7 * 4096;
    float* tpart   = fb + 8 * 4096;        // 8*4096 floats
    float* outpart = fb + 16 * 4096;       // 128 floats
    int*   bar     = (int*)(fb + 16 * 4096 + 128);

    void* args[] = {&x, &y, &out, &K0, &xsq, &ysq, &Ea, &Eb, &uu, &vv, &ut, &vt,
                    &tpart, &outpart, &bar};

    hipError_t err = hipLaunchCooperativeKernel((void*)sinkhorn_all, dim3(NB), dim3(1024),
                                                (void**)args, 0, stream);
    if (err != hipSuccess)
        (void)hipLaunchCooperativeKernel((void*)sinkhorn_all, dim3(NB), dim3(1024),
                                         (void**)args, 0, stream);
}

// Round 5
// 1411.215 us; speedup vs baseline: 5.0194x; 1.0193x over previous
//
#include <hip/hip_runtime.h>
#include <hip/hip_cooperative_groups.h>

namespace cg = cooperative_groups;

typedef unsigned char u8;
typedef unsigned short u16;
typedef unsigned int u32;

#define NN 4096
#define NITER 50
#define REGE 10.0f
#define TAUV 1000.0f
#define AMARG (1.0f / 4096.0f)
#define EPSS 1e-16f
#define NB 256   // blocks (stripe arithmetic depends on it)
#define NG 16    // barrier groups
#define GS 16    // blocks per group
#define KSCL 4096.0f             // K stored as Q = K * 2^12 in fp8-e5m2
#define KLN2 8.317766166719343f  // 12 * ln(2)

__device__ __forceinline__ float wsum(float v) {
#pragma unroll
    for (int off = 32; off; off >>= 1) v += __shfl_xor(v, off, 64);
    return v;
}
// e5m2 encode from f32: f32 -> f16 (RNE, handles subnormals) -> round mantissa to 2 bits.
__device__ __forceinline__ u8 f2e5(float f) {
    union { _Float16 h; u16 u; } cv; cv.h = (_Float16)f;
    const u16 h = cv.u;
    return (u8)((h + 0x7F + ((h >> 8) & 1)) >> 8);
}
// e5m2 is truncated fp16: decode = byte<<8 reinterpret as half -> f32 (exact, incl. subnormals)
__device__ __forceinline__ float e52f(u32 b) {
    union { u16 u; _Float16 h; } cv; cv.u = (u16)(b << 8);
    return (float)cv.h;
}
__device__ __forceinline__ void dec4(u32 w, float* o) {
    o[0] = e52f(w & 0xffu);
    o[1] = e52f((w >> 8) & 0xffu);
    o[2] = e52f((w >> 16) & 0xffu);
    o[3] = e52f(w >> 24);
}

// Agent-scope (L1/L2-bypassing, L3-coherent) ops; RELAXED => no cache maintenance
// => K0 stripes stay L2-resident.
__device__ __forceinline__ float agent_ldf(const float* p) {
    return __hip_atomic_load(p, __ATOMIC_RELAXED, __HIP_MEMORY_SCOPE_AGENT);
}
__device__ __forceinline__ void agent_stf(float* p, float v) {
    __hip_atomic_store(p, v, __ATOMIC_RELAXED, __HIP_MEMORY_SCOPE_AGENT);
}
__device__ __forceinline__ int agent_ldi(const int* p) {
    return __hip_atomic_load(p, __ATOMIC_RELAXED, __HIP_MEMORY_SCOPE_AGENT);
}
__device__ __forceinline__ void agent_sti(int* p, int v) {
    __hip_atomic_store(p, v, __ATOMIC_RELAXED, __HIP_MEMORY_SCOPE_AGENT);
}

// Two-level grid barrier (verified R3/R4). Arrival relies on __syncthreads'
// vmcnt(0) drain: all sc1 stores are L3-visible before the counter bump.
__device__ __forceinline__ void gbar(int* arr, int* root, int* rel,
                                     int g, int ep, int tid) {
    __syncthreads();
    if (tid == 0) {
        asm volatile("s_waitcnt vmcnt(0)" ::: "memory");
        const int old = __hip_atomic_fetch_add(arr + g * 32, 1,
                                               __ATOMIC_RELAXED, __HIP_MEMORY_SCOPE_AGENT);
        if (old == GS * ep - 1) {
            const int r = __hip_atomic_fetch_add(root, 1,
                                                 __ATOMIC_RELAXED, __HIP_MEMORY_SCOPE_AGENT);
            if (r == NG * ep - 1) {
#pragma unroll
                for (int i = 0; i < NG; ++i) agent_sti(rel + i * 32, ep);
            } else {
                while (agent_ldi(rel + g * 32) < ep) __builtin_amdgcn_s_sleep(1);
            }
        } else {
            while (agent_ldi(rel + g * 32) < ep) __builtin_amdgcn_s_sleep(1);
        }
    }
    __syncthreads();
}

__global__ __launch_bounds__(1024, 8) void sinkhorn_all(
    const float* __restrict__ x, const float* __restrict__ y, float* __restrict__ out,
    u8* __restrict__ K0,
    float* __restrict__ xsq, float* __restrict__ ysq,
    float* __restrict__ Ea, float* __restrict__ Eb,
    float* __restrict__ uu, float* __restrict__ vv,
    float* __restrict__ ut, float* __restrict__ vt,
    float* __restrict__ tpart, float* __restrict__ outpart,
    int* __restrict__ bar) {
    cg::grid_group grid = cg::this_grid();
    union Sh {
        struct { float xs[64][65]; float ys[64][65]; } bld;   // setup tiles
        struct {
            float vtl[NN + 256];        // padded vector stage (B / final)
            float psum[16][16][8];      // A: per-wave partials
            float psh[16];              // final: per-wave partials
            float uts[512];             // A: ut stripe slice
        } it;
    };
    __shared__ Sh sh;
    __shared__ int ibc;       // absorb-flag broadcast
    __shared__ int oldc_sh;   // last-finisher broadcast

    const int tid  = threadIdx.x;
    const int lane = tid & 63;
    const int wid  = tid >> 6;     // 0..15
    const int b    = blockIdx.x;
    const int c    = b & 7;        // stripe (rows [512c, 512c+512) of K0)
    const int l    = b >> 3;       // 0..31: chunk within stripe
    const int g    = b >> 4;       // barrier group

    int* flags = bar;                        // [0..2] absorb flags
    int* arr   = bar + 32;                   // NG lines
    int* root  = bar + 32 + NG * 32;
    int* rel   = bar + 64 + NG * 32;
    int* done  = bar + 64 + 2 * NG * 32;     // 32 chunk counters, 16-int spacing

    // ---------------- S0: row norms + state init ----------------
    for (int r = b * 16 + wid; r < 2 * NN; r += NB * 16) {
        const float* src = (r < NN) ? (x + (size_t)r * 64) : (y + (size_t)(r - NN) * 64);
        float t = src[lane];
        float s = wsum(t * t);
        if (lane == 0) { if (r < NN) xsq[r] = s; else ysq[r - NN] = s; }
    }
    {
        const int gt = b * 1024 + tid;
        if (gt < NN) {
            Ea[gt] = 1.f; Eb[gt] = 1.f; uu[gt] = AMARG; vv[gt] = AMARG;
            ut[gt] = AMARG; vt[gt] = AMARG;
        }
    }
    if (b == 0) {
        if (tid < NG) { arr[tid * 32] = 0; rel[tid * 32] = 0; }
        if (tid < 32) done[tid * 16] = 0;
        if (tid < 8) outpart[tid * 16] = 0.f;
        if (tid == 0) { *root = 0; flags[0] = 0; flags[1] = 0; flags[2] = 0; }
    }
    grid.sync();   // full fence: init visible, stale poison lines cleared

    // ------- S1: Q = K*2^12 = exp2(12 - M*log2e/10) in e5m2, stripe-aligned -------
    {
        const int tx = tid & 31, ty = tid >> 5;   // 32x32 threads, 2x2 out each
        for (int q = 0; q < 16; ++q) {
            const int s = l * 16 + q;             // tile within stripe c
            const int i0 = (8 * c + (s >> 6)) * 64;
            const int j0 = (s & 63) * 64;
            __syncthreads();
            {
                const int row = tid >> 4, col4 = (tid & 15) * 4;
                *(float4*)&sh.bld.xs[row][col4] = *(const float4*)(x + (size_t)(i0 + row) * 64 + col4);
                *(float4*)&sh.bld.ys[row][col4] = *(const float4*)(y + (size_t)(j0 + row) * 64 + col4);
            }
            __syncthreads();
            float a00 = 0, a01 = 0, a10 = 0, a11 = 0;
#pragma unroll
            for (int k = 0; k < 64; ++k) {
                const float x0 = sh.bld.xs[ty * 2][k],     x1 = sh.bld.xs[ty * 2 + 1][k];
                const float y0 = sh.bld.ys[tx * 2][k],     y1 = sh.bld.ys[tx * 2 + 1][k];
                a00 = __fmaf_rn(x0, y0, a00); a01 = __fmaf_rn(x0, y1, a01);
                a10 = __fmaf_rn(x1, y0, a10); a11 = __fmaf_rn(x1, y1, a11);
            }
            const float xq0 = xsq[i0 + ty * 2], xq1 = xsq[i0 + ty * 2 + 1];
            const float yq0 = ysq[j0 + tx * 2], yq1 = ysq[j0 + tx * 2 + 1];
            const float C = 0.14426950408889634f;   // log2(e)/10
            const u8 q00 = f2e5(exp2f(12.f - (xq0 + yq0 - 2.f * a00) * C));
            const u8 q01 = f2e5(exp2f(12.f - (xq0 + yq1 - 2.f * a01) * C));
            const u8 q10 = f2e5(exp2f(12.f - (xq1 + yq0 - 2.f * a10) * C));
            const u8 q11 = f2e5(exp2f(12.f - (xq1 + yq1 - 2.f * a11) * C));
            *(u16*)(K0 + (size_t)(i0 + ty * 2) * NN + j0 + tx * 2)     = (u16)(q00 | (q01 << 8));
            *(u16*)(K0 + (size_t)(i0 + ty * 2 + 1) * NN + j0 + tx * 2) = (u16)(q10 | (q11 << 8));
        }
    }
    grid.sync();   // K0 visible everywhere; read-only hereafter

    // ---------------- 50 Sinkhorn iterations ----------------
    int ep = 0;
    for (int it = 0; it < NITER; ++it) {
        const int fprev = (it + 2) % 3;
        const int fcur  = it % 3;
        const int fnext = (it + 1) % 3;
        if (tid == 0) {
            ibc = agent_ldi(flags + fprev);
            if (b == 0) agent_sti(flags + fnext, 0);
        }
        __syncthreads();
        const bool absorb = ibc != 0;
        const float su = absorb ? AMARG : 1.f;

        // ---- Phase A: t_j partials over stripe-c rows, j in [128l,128l+128) ----
        {
            const int jj = tid & 15, gg = tid >> 4;   // 8 j-cols, 8 i-rows each
            const u8* kbase = K0 + (size_t)(512 * c + 8 * gg) * NN + 128 * l + 8 * jj;
            uint2 kr[8];
#pragma unroll
            for (int ii = 0; ii < 8; ++ii)            // K loads first: overlap sc1 stage
                kr[ii] = *(const uint2*)(kbase + (size_t)ii * NN);
            if (tid < 512) sh.it.uts[tid] = agent_ldf(ut + 512 * c + tid);
            __syncthreads();
            float acc[8] = {};
#pragma unroll
            for (int ii = 0; ii < 8; ++ii) {
                const float ui = sh.it.uts[8 * gg + ii];
                float qv[8];
                dec4(kr[ii].x, qv); dec4(kr[ii].y, qv + 4);
#pragma unroll
                for (int k = 0; k < 8; ++k) acc[k] = __fmaf_rn(qv[k], ui, acc[k]);
            }
#pragma unroll
            for (int k = 0; k < 8; ++k) {   // combine 4 row-subgroups within wave
                acc[k] += __shfl_xor(acc[k], 16, 64);
                acc[k] += __shfl_xor(acc[k], 32, 64);
            }
            if ((lane >> 4) == 0) {
#pragma unroll
                for (int k = 0; k < 8; ++k) sh.it.psum[wid][lane][k] = acc[k];
            }
        }
        __syncthreads();
        if (tid < 128) {
            float tot = 0.f;
#pragma unroll
            for (int w = 0; w < 16; ++w) tot += sh.it.psum[w][tid >> 3][tid & 7];
            agent_stf(tpart + c * NN + 128 * l + tid, tot);   // coalesced sc1
        }
        __syncthreads();   // drains vmcnt: partial stores L3-visible
        if (tid == 0)
            oldc_sh = __hip_atomic_fetch_add(done + l * 16, 1,
                                             __ATOMIC_RELAXED, __HIP_MEMORY_SCOPE_AGENT);
        __syncthreads();
        if (oldc_sh == 8 * (it + 1) - 1 && tid < 128) {
            // last finisher for chunk l: all 8 stripe partials are visible
            const int j = 128 * l + tid;
            float tj = 0.f;
#pragma unroll
            for (int cc = 0; cc < 8; ++cc) tj += agent_ldf(tpart + cc * NN + j);
            tj *= (1.0f / KSCL);                      // undo Q = K*2^12
            float E = agent_ldf(Eb + j);
            if (absorb) { E *= agent_ldf(vv + j); agent_stf(Eb + j, E); }
            const float vj = AMARG / (E * (tj * su) + EPSS);
            agent_stf(vv + j, vj);
            agent_stf(vt + j, E * vj);
            if (vj > TAUV && agent_ldi(flags + fcur) == 0)
                (void)__hip_atomic_fetch_or(flags + fcur, 1,
                                            __ATOMIC_RELAXED, __HIP_MEMORY_SCOPE_AGENT);
        }
        ++ep; gbar(arr, root, rel, g, ep, tid);

        // ---- Phase B: full row-dots, rows i = 512c+16l+[0,16) ----
        {
            const int i = 512 * c + 16 * l + wid;
            const u8* krow = K0 + (size_t)i * NN;
            uint4 kq[4];
#pragma unroll
            for (int seg = 0; seg < 4; ++seg)         // K loads first: overlap sc1 stage
                kq[seg] = *(const uint4*)(krow + seg * 1024 + lane * 16);
#pragma unroll
            for (int m = 0; m < 4; ++m) {
                const int j = m * 1024 + tid;
                sh.it.vtl[j + (j >> 4)] = agent_ldf(vt + j);
            }
            __syncthreads();
            float s = 0.f;
#pragma unroll
            for (int seg = 0; seg < 4; ++seg) {
                const int j0 = seg * 1024 + lane * 16;
                const float* vp = &sh.it.vtl[j0 + (j0 >> 4)];
                float qv[16];
                dec4(kq[seg].x, qv);      dec4(kq[seg].y, qv + 4);
                dec4(kq[seg].z, qv + 8);  dec4(kq[seg].w, qv + 12);
#pragma unroll
                for (int k = 0; k < 16; ++k) s = __fmaf_rn(qv[k], vp[k], s);
            }
            s = wsum(s) * (1.0f / KSCL);
            if (lane == 0) {
                float E = Ea[i];                      // block-private, cached
                if (absorb) { E *= uu[i]; Ea[i] = E; }
                const float u2 = AMARG / (E * s + EPSS);
                uu[i] = u2;
                agent_stf(ut + i, E * u2);
                if (u2 > TAUV && agent_ldi(flags + fcur) == 0)
                    (void)__hip_atomic_fetch_or(flags + fcur, 1,
                                                __ATOMIC_RELAXED, __HIP_MEMORY_SCOPE_AGENT);
            }
        }
        ++ep; gbar(arr, root, rel, g, ep, tid);
    }

    // -------- F: loss = scale * sum_ij K*(-eps log K)*ut_i*vt_j,  K = Q*2^-12 ----
    // per row: ut_i * 2^-12 * (-eps) * (sum Q logQ vt - 12ln2 * sum Q vt)
    if (tid == 0) ibc = agent_ldi(flags + (NITER + 2) % 3);
    __syncthreads();
    const float scale = ibc ? (AMARG * AMARG) : 1.f;

    {
        const int i = 512 * c + 16 * l + wid;
        const u8* krow = K0 + (size_t)i * NN;
        uint4 kq[4];
#pragma unroll
        for (int seg = 0; seg < 4; ++seg)
            kq[seg] = *(const uint4*)(krow + seg * 1024 + lane * 16);
#pragma unroll
        for (int m = 0; m < 4; ++m) {
            const int j = m * 1024 + tid;
            sh.it.vtl[j + (j >> 4)] = agent_ldf(vt + j);
        }
        __syncthreads();
        float a1 = 0.f, a2 = 0.f;
#pragma unroll
        for (int seg = 0; seg < 4; ++seg) {
            const int j0 = seg * 1024 + lane * 16;
            const float* vp = &sh.it.vtl[j0 + (j0 >> 4)];
            float qv[16];
            dec4(kq[seg].x, qv);      dec4(kq[seg].y, qv + 4);
            dec4(kq[seg].z, qv + 8);  dec4(kq[seg].w, qv + 12);
#pragma unroll
            for (int k = 0; k < 16; ++k) {
                const float q = qv[k];
                a2 = __fmaf_rn(q, vp[k], a2);
                a1 = __fmaf_rn(q * __logf(fmaxf(q, 1e-30f)), vp[k], a1);  // q=0 -> 0
            }
        }
        a1 = wsum(a1); a2 = wsum(a2);
        if (lane == 0) sh.it.psh[wid] = (a1 - KLN2 * a2) * agent_ldf(ut + i);
    }
    __syncthreads();
    if (tid == 0) {
        float bacc = 0.f;
#pragma unroll
        for (int w = 0; w < 16; ++w) bacc += sh.it.psh[w];
        (void)__hip_atomic_fetch_add(outpart + (b & 7) * 16, bacc,
                                     __ATOMIC_RELAXED, __HIP_MEMORY_SCOPE_AGENT);
    }
    ++ep; gbar(arr, root, rel, g, ep, tid);
    if (b == 0 && tid == 0) {
        float tot = 0.f;
#pragma unroll
        for (int k = 0; k < 8; ++k) tot += agent_ldf(outpart + k * 16);
        out[0] = tot * (-REGE / KSCL) * scale;
    }
}

extern "C" void kernel_launch(void* const* d_in, const int* in_sizes, int n_in,
                              void* d_out, int out_size, void* d_ws, size_t ws_size,
                              hipStream_t stream) {
    const float* x = (const float*)d_in[0];
    const float* y = (const float*)d_in[1];
    float* out = (float*)d_out;
    char* ws = (char*)d_ws;

    // ws: K0 fp8-e5m2 16MB | 8 fp32 vectors of 4096 | tpart[8][4096] | outpart | bar ints
    u8* K0 = (u8*)(ws);
    float* fb = (float*)(ws + 16777216ull);
    float* xsq = fb + 0 * 4096;
    float* ysq = fb + 1 * 4096;
    float* Ea  = fb + 2 * 4096;
    float* Eb  = fb + 3 * 4096;
    float* uu  = fb + 4 * 4096;
    float* vv  = fb + 5 * 4096;
    float* ut  = fb + 6 * 4096;
    float* vt  = fb + 7 * 4096;
    float* tpart   = fb + 8 * 4096;        // 8*4096 floats
    float* outpart = fb + 16 * 4096;       // 128 floats
    int*   bar     = (int*)(fb + 16 * 4096 + 128);

    void* args[] = {&x, &y, &out, &K0, &xsq, &ysq, &Ea, &Eb, &uu, &vv, &ut, &vt,
                    &tpart, &outpart, &bar};

    hipError_t err = hipLaunchCooperativeKernel((void*)sinkhorn_all, dim3(NB), dim3(1024),
                                                (void**)args, 0, stream);
    if (err != hipSuccess)
        (void)hipLaunchCooperativeKernel((void*)sinkhorn_all, dim3(NB), dim3(1024),
                                         (void**)args, 0, stream);
}

// Round 6
// 1136.131 us; speedup vs baseline: 6.2347x; 1.2421x over previous
//
#include <hip/hip_runtime.h>
#include <hip/hip_cooperative_groups.h>

namespace cg = cooperative_groups;

typedef unsigned char u8;
typedef unsigned short u16;
typedef unsigned int u32;

#define NN 4096
#define NITER 50
#define REGE 10.0f
#define TAUV 1000.0f
#define AMARG (1.0f / 4096.0f)
#define EPSS 1e-16f
#define NB 256   // blocks (region arithmetic depends on it)
#define NG 16    // barrier groups
#define GS 16    // blocks per group
#define KSCL 4096.0f             // K stored as Q = K * 2^12 in fp8-e5m2
#define KLN2 8.317766166719343f  // 12 * ln(2)

__device__ __forceinline__ float wsum(float v) {
#pragma unroll
    for (int off = 32; off; off >>= 1) v += __shfl_xor(v, off, 64);
    return v;
}
// e5m2 encode: f32 -> f16 (RNE) -> round mantissa to 2 bits (RNE).
__device__ __forceinline__ u8 f2e5(float f) {
    union { _Float16 h; u16 u; } cv; cv.h = (_Float16)f;
    const u16 h = cv.u;
    return (u8)((h + 0x7F + ((h >> 8) & 1)) >> 8);
}
// e5m2 = truncated fp16: decode exact (incl. subnormals)
__device__ __forceinline__ float e52f(u32 b) {
    union { u16 u; _Float16 h; } cv; cv.u = (u16)(b << 16 >> 16 << 8);  // (b&0xff)<<8
    return (float)cv.h;
}
__device__ __forceinline__ void dec4(u32 w, float* o) {
    o[0] = e52f(w & 0xffu);
    o[1] = e52f((w >> 8) & 0xffu);
    o[2] = e52f((w >> 16) & 0xffu);
    o[3] = e52f(w >> 24);
}

// Agent-scope (L1/L2-bypassing, L3-coherent) ops; RELAXED => no cache
// maintenance => K0 regions stay L2-resident.
__device__ __forceinline__ float agent_ldf(const float* p) {
    return __hip_atomic_load(p, __ATOMIC_RELAXED, __HIP_MEMORY_SCOPE_AGENT);
}
__device__ __forceinline__ void agent_stf(float* p, float v) {
    __hip_atomic_store(p, v, __ATOMIC_RELAXED, __HIP_MEMORY_SCOPE_AGENT);
}
__device__ __forceinline__ int agent_ldi(const int* p) {
    return __hip_atomic_load(p, __ATOMIC_RELAXED, __HIP_MEMORY_SCOPE_AGENT);
}
__device__ __forceinline__ void agent_sti(int* p, int v) {
    __hip_atomic_store(p, v, __ATOMIC_RELAXED, __HIP_MEMORY_SCOPE_AGENT);
}

// Two-level grid barrier (verified R3-R5). Arrival relies on __syncthreads'
// per-wave vmcnt drain: all sc1 stores are L3-visible before the counter bump.
__device__ __forceinline__ void gbar(int* arr, int* root, int* rel,
                                     int g, int ep, int tid) {
    __syncthreads();
    if (tid == 0) {
        asm volatile("s_waitcnt vmcnt(0)" ::: "memory");
        const int old = __hip_atomic_fetch_add(arr + g * 32, 1,
                                               __ATOMIC_RELAXED, __HIP_MEMORY_SCOPE_AGENT);
        if (old == GS * ep - 1) {
            const int r = __hip_atomic_fetch_add(root, 1,
                                                 __ATOMIC_RELAXED, __HIP_MEMORY_SCOPE_AGENT);
            if (r == NG * ep - 1) {
#pragma unroll
                for (int i = 0; i < NG; ++i) agent_sti(rel + i * 32, ep);
            } else {
                while (agent_ldi(rel + g * 32) < ep) __builtin_amdgcn_s_sleep(1);
            }
        } else {
            while (agent_ldi(rel + g * 32) < ep) __builtin_amdgcn_s_sleep(1);
        }
    }
    __syncthreads();
}

__global__ __launch_bounds__(1024, 4) void sinkhorn_all(
    const float* __restrict__ x, const float* __restrict__ y, float* __restrict__ out,
    u8* __restrict__ K0,
    float* __restrict__ xsq, float* __restrict__ ysq,
    float* __restrict__ Ea, float* __restrict__ Eb,
    float* __restrict__ uu, float* __restrict__ vv,
    float* __restrict__ ut, float* __restrict__ vt,
    float* __restrict__ tpart, float* __restrict__ spart,
    float* __restrict__ outpart, int* __restrict__ bar) {
    cg::grid_group grid = cg::this_grid();
    union Sh {
        struct { float xs[64][65]; float ys[64][65]; } bld;   // setup tiles (33 KB)
        struct {
            float uts[512];             // A: ut stripe slice
            float psumA[16][16][8];     // A: per-wave partials
            float vtl[128];             // B/F: vt chunk
            float rowsum[512];          // B: per-row partials (repack for store)
            float psh[16];              // F: per-wave partials
        } it;                           // ~13 KB
    };
    __shared__ Sh sh;
    __shared__ int ibc;       // absorb-flag broadcast
    __shared__ int oldc_sh;   // last-finisher broadcast

    const int tid  = threadIdx.x;
    const int lane = tid & 63;
    const int wid  = tid >> 6;     // 0..15
    const int b    = blockIdx.x;
    const int c    = b & 7;        // stripe: rows [512c, 512c+512)
    const int l    = b >> 3;       // 0..31: col-chunk [128l, 128l+128)
    const int g    = b >> 4;       // barrier group

    // bar layout (ints): flags[0..2] | arr @32 (16 lines) | root @544 |
    // rel @576 (16 lines) | doneA @1088 (32 ctrs x16) | doneB @1600 (8 ctrs x16)
    int* flags = bar;
    int* arr   = bar + 32;
    int* root  = bar + 544;
    int* rel   = bar + 576;
    int* doneA = bar + 1088;
    int* doneB = bar + 1600;

    // ---------------- S0: row norms + state init ----------------
    for (int r = b * 16 + wid; r < 2 * NN; r += NB * 16) {
        const float* src = (r < NN) ? (x + (size_t)r * 64) : (y + (size_t)(r - NN) * 64);
        float t = src[lane];
        float s = wsum(t * t);
        if (lane == 0) { if (r < NN) xsq[r] = s; else ysq[r - NN] = s; }
    }
    {
        const int gt = b * 1024 + tid;
        if (gt < NN) {
            Ea[gt] = 1.f; Eb[gt] = 1.f; uu[gt] = AMARG; vv[gt] = AMARG;
            ut[gt] = AMARG; vt[gt] = AMARG;
        }
    }
    if (b == 0) {
        for (int z = tid; z < 1728; z += 1024) bar[z] = 0;
        if (tid < 8) outpart[tid * 16] = 0.f;
    }
    grid.sync();   // full fence: init visible, stale poison lines cleared

    // ---- S1: build Q = K*2^12 = exp2(12 - M*log2e/10) e5m2, REGION-ALIGNED ----
    // Block (c,l) builds exactly the 512x128 region it reads in every phase.
    {
        const int tx = tid & 31, ty = tid >> 5;   // 32x32 threads, 2x2 out each
        for (int t = 0; t < 16; ++t) {
            const int rt = t >> 1, ct = t & 1;
            const int i0 = 512 * c + 64 * rt;
            const int j0 = 128 * l + 64 * ct;
            __syncthreads();
            {
                const int row = tid >> 4, col4 = (tid & 15) * 4;
                *(float4*)&sh.bld.xs[row][col4] = *(const float4*)(x + (size_t)(i0 + row) * 64 + col4);
                *(float4*)&sh.bld.ys[row][col4] = *(const float4*)(y + (size_t)(j0 + row) * 64 + col4);
            }
            __syncthreads();
            float a00 = 0, a01 = 0, a10 = 0, a11 = 0;
#pragma unroll
            for (int k = 0; k < 64; ++k) {
                const float x0 = sh.bld.xs[ty * 2][k],     x1 = sh.bld.xs[ty * 2 + 1][k];
                const float y0 = sh.bld.ys[tx * 2][k],     y1 = sh.bld.ys[tx * 2 + 1][k];
                a00 = __fmaf_rn(x0, y0, a00); a01 = __fmaf_rn(x0, y1, a01);
                a10 = __fmaf_rn(x1, y0, a10); a11 = __fmaf_rn(x1, y1, a11);
            }
            const float xq0 = xsq[i0 + ty * 2], xq1 = xsq[i0 + ty * 2 + 1];
            const float yq0 = ysq[j0 + tx * 2], yq1 = ysq[j0 + tx * 2 + 1];
            const float C = 0.14426950408889634f;   // log2(e)/10
            const u8 q00 = f2e5(exp2f(12.f - (xq0 + yq0 - 2.f * a00) * C));
            const u8 q01 = f2e5(exp2f(12.f - (xq0 + yq1 - 2.f * a01) * C));
            const u8 q10 = f2e5(exp2f(12.f - (xq1 + yq0 - 2.f * a10) * C));
            const u8 q11 = f2e5(exp2f(12.f - (xq1 + yq1 - 2.f * a11) * C));
            *(u16*)(K0 + (size_t)(i0 + ty * 2) * NN + j0 + tx * 2)     = (u16)(q00 | (q01 << 8));
            *(u16*)(K0 + (size_t)(i0 + ty * 2 + 1) * NN + j0 + tx * 2) = (u16)(q10 | (q11 << 8));
        }
    }
    grid.sync();   // K0 visible; read-only hereafter

    // ---------------- 50 Sinkhorn iterations ----------------
    int ep = 0;
    for (int it = 0; it < NITER; ++it) {
        const int fprev = (it + 2) % 3;
        const int fcur  = it % 3;
        const int fnext = (it + 1) % 3;
        if (tid == 0) {
            ibc = agent_ldi(flags + fprev);
            if (b == 0) agent_sti(flags + fnext, 0);
        }
        __syncthreads();
        const bool absorb = ibc != 0;
        const float su = absorb ? AMARG : 1.f;

        // ---- Phase A: col-sum partials t_j over region rows ----
        {
            const int jj = tid & 15, gg = tid >> 4;   // 8 cols, 8 rows each
            const u8* kbase = K0 + (size_t)(512 * c + 8 * gg) * NN + 128 * l + 8 * jj;
            uint2 kr[8];
#pragma unroll
            for (int ii = 0; ii < 8; ++ii)            // K loads first (MLP)
                kr[ii] = *(const uint2*)(kbase + (size_t)ii * NN);
            if (tid < 512) sh.it.uts[tid] = agent_ldf(ut + 512 * c + tid);
            __syncthreads();
            float acc[8] = {};
#pragma unroll
            for (int ii = 0; ii < 8; ++ii) {
                const float ui = sh.it.uts[8 * gg + ii];
                float qv[8];
                dec4(kr[ii].x, qv); dec4(kr[ii].y, qv + 4);
#pragma unroll
                for (int k = 0; k < 8; ++k) acc[k] = __fmaf_rn(qv[k], ui, acc[k]);
            }
#pragma unroll
            for (int k = 0; k < 8; ++k) {
                acc[k] += __shfl_xor(acc[k], 16, 64);
                acc[k] += __shfl_xor(acc[k], 32, 64);
            }
            if ((lane >> 4) == 0) {
#pragma unroll
                for (int k = 0; k < 8; ++k) sh.it.psumA[wid][lane][k] = acc[k];
            }
        }
        __syncthreads();
        if (tid < 128) {
            float tot = 0.f;
#pragma unroll
            for (int w = 0; w < 16; ++w) tot += sh.it.psumA[w][tid >> 3][tid & 7];
            agent_stf(tpart + c * NN + 128 * l + tid, tot);
        }
        __syncthreads();   // drains vmcnt: partials L3-visible
        if (tid == 0)
            oldc_sh = __hip_atomic_fetch_add(doneA + l * 16, 1,
                                             __ATOMIC_RELAXED, __HIP_MEMORY_SCOPE_AGENT);
        __syncthreads();
        if (oldc_sh == 8 * (it + 1) - 1 && tid < 128) {
            // last finisher for col-chunk l: combine 8 stripe partials
            const int j = 128 * l + tid;
            float tj = 0.f;
#pragma unroll
            for (int cc = 0; cc < 8; ++cc) tj += agent_ldf(tpart + cc * NN + j);
            tj *= (1.0f / KSCL);
            float E = agent_ldf(Eb + j);
            if (absorb) { E *= agent_ldf(vv + j); agent_stf(Eb + j, E); }
            const float vj = AMARG / (E * (tj * su) + EPSS);
            agent_stf(vv + j, vj);
            agent_stf(vt + j, E * vj);
            if (vj > TAUV && agent_ldi(flags + fcur) == 0)
                (void)__hip_atomic_fetch_or(flags + fcur, 1,
                                            __ATOMIC_RELAXED, __HIP_MEMORY_SCOPE_AGENT);
        }
        ++ep; gbar(arr, root, rel, g, ep, tid);

        // ---- Phase B: row-sum partials s_i over region cols (SAME 64 KB) ----
        {
            const int r = tid >> 1, h = tid & 1;      // 2 threads/row, 64 cols each
            const u8* kb = K0 + (size_t)(512 * c + r) * NN + 128 * l + 64 * h;
            uint4 kq[4];
#pragma unroll
            for (int s4 = 0; s4 < 4; ++s4)            // K loads first (MLP)
                kq[s4] = *(const uint4*)(kb + s4 * 16);
            if (tid < 128) sh.it.vtl[tid] = agent_ldf(vt + 128 * l + tid);
            __syncthreads();
            float s = 0.f;
#pragma unroll
            for (int s4 = 0; s4 < 4; ++s4) {
                float qv[16];
                dec4(kq[s4].x, qv);      dec4(kq[s4].y, qv + 4);
                dec4(kq[s4].z, qv + 8);  dec4(kq[s4].w, qv + 12);
                const float* vp = &sh.it.vtl[64 * h + s4 * 16];
#pragma unroll
                for (int k = 0; k < 16; ++k) s = __fmaf_rn(qv[k], vp[k], s);
            }
            s += __shfl_xor(s, 1, 64);
            if (h == 0) sh.it.rowsum[r] = s;
        }
        __syncthreads();
        if (tid < 512)
            agent_stf(spart + (size_t)(c * 32 + l) * 512 + tid, sh.it.rowsum[tid]);
        __syncthreads();   // drains vmcnt
        if (tid == 0)
            oldc_sh = __hip_atomic_fetch_add(doneB + c * 16, 1,
                                             __ATOMIC_RELAXED, __HIP_MEMORY_SCOPE_AGENT);
        __syncthreads();
        if (oldc_sh == 32 * (it + 1) - 1) {
            // last finisher for stripe c: combine 32 chunk partials per row
            const int r = tid >> 1, h = tid & 1;
            float sp[16];
#pragma unroll
            for (int k = 0; k < 16; ++k)
                sp[k] = agent_ldf(spart + (size_t)(c * 32 + h * 16 + k) * 512 + r);
            float si = 0.f;
#pragma unroll
            for (int k = 0; k < 16; ++k) si += sp[k];
            si += __shfl_xor(si, 1, 64);
            if (h == 0) {
                const int i = 512 * c + r;
                si *= (1.0f / KSCL);
                float E = agent_ldf(Ea + i);
                if (absorb) { E *= agent_ldf(uu + i); agent_stf(Ea + i, E); }
                const float u2 = AMARG / (E * si + EPSS);
                agent_stf(uu + i, u2);
                agent_stf(ut + i, E * u2);
                if (u2 > TAUV && agent_ldi(flags + fcur) == 0)
                    (void)__hip_atomic_fetch_or(flags + fcur, 1,
                                                __ATOMIC_RELAXED, __HIP_MEMORY_SCOPE_AGENT);
            }
        }
        ++ep; gbar(arr, root, rel, g, ep, tid);
    }

    // ------ F: loss = scale*sum_ij K*(-eps log K)*ut_i*vt_j over own region ------
    if (tid == 0) ibc = agent_ldi(flags + (NITER + 2) % 3);
    __syncthreads();
    const float scale = ibc ? (AMARG * AMARG) : 1.f;
    {
        const int r = tid >> 1, h = tid & 1;
        const int i = 512 * c + r;
        const u8* kb = K0 + (size_t)i * NN + 128 * l + 64 * h;
        uint4 kq[4];
#pragma unroll
        for (int s4 = 0; s4 < 4; ++s4)
            kq[s4] = *(const uint4*)(kb + s4 * 16);
        if (tid < 128) sh.it.vtl[tid] = agent_ldf(vt + 128 * l + tid);
        __syncthreads();
        float a1 = 0.f, a2 = 0.f;
#pragma unroll
        for (int s4 = 0; s4 < 4; ++s4) {
            float qv[16];
            dec4(kq[s4].x, qv);      dec4(kq[s4].y, qv + 4);
            dec4(kq[s4].z, qv + 8);  dec4(kq[s4].w, qv + 12);
            const float* vp = &sh.it.vtl[64 * h + s4 * 16];
#pragma unroll
            for (int k = 0; k < 16; ++k) {
                const float q = qv[k];
                a2 = __fmaf_rn(q, vp[k], a2);
                a1 = __fmaf_rn(q * __logf(fmaxf(q, 1e-30f)), vp[k], a1);
            }
        }
        a1 += __shfl_xor(a1, 1, 64);
        a2 += __shfl_xor(a2, 1, 64);
        float rowv = (h == 0) ? (a1 - KLN2 * a2) * agent_ldf(ut + i) : 0.f;
        rowv = wsum(rowv);
        if (lane == 0) sh.it.psh[wid] = rowv;
    }
    __syncthreads();
    if (tid == 0) {
        float bacc = 0.f;
#pragma unroll
        for (int w = 0; w < 16; ++w) bacc += sh.it.psh[w];
        (void)__hip_atomic_fetch_add(outpart + c * 16, bacc,
                                     __ATOMIC_RELAXED, __HIP_MEMORY_SCOPE_AGENT);
    }
    ++ep; gbar(arr, root, rel, g, ep, tid);
    if (b == 0 && tid == 0) {
        float tot = 0.f;
#pragma unroll
        for (int k = 0; k < 8; ++k) tot += agent_ldf(outpart + k * 16);
        out[0] = tot * (-REGE / KSCL) * scale;
    }
}

extern "C" void kernel_launch(void* const* d_in, const int* in_sizes, int n_in,
                              void* d_out, int out_size, void* d_ws, size_t ws_size,
                              hipStream_t stream) {
    const float* x = (const float*)d_in[0];
    const float* y = (const float*)d_in[1];
    float* out = (float*)d_out;
    char* ws = (char*)d_ws;

    // ws: K0 e5m2 16MB | 8 fp32 vecs of 4096 | tpart 8x4096 | spart 8x32x512 |
    //     outpart 128 | bar 1728 ints
    u8* K0 = (u8*)(ws);
    float* fb = (float*)(ws + 16777216ull);
    float* xsq = fb + 0 * 4096;
    float* ysq = fb + 1 * 4096;
    float* Ea  = fb + 2 * 4096;
    float* Eb  = fb + 3 * 4096;
    float* uu  = fb + 4 * 4096;
    float* vv  = fb + 5 * 4096;
    float* ut  = fb + 6 * 4096;
    float* vt  = fb + 7 * 4096;
    float* tpart   = fb + 8 * 4096;        // 32768 floats
    float* spart   = fb + 16 * 4096;       // 131072 floats
    float* outpart = fb + 48 * 4096;       // 128 floats
    int*   bar     = (int*)(fb + 48 * 4096 + 128);

    void* args[] = {&x, &y, &out, &K0, &xsq, &ysq, &Ea, &Eb, &uu, &vv, &ut, &vt,
                    &tpart, &spart, &outpart, &bar};

    hipError_t err = hipLaunchCooperativeKernel((void*)sinkhorn_all, dim3(NB), dim3(1024),
                                                (void**)args, 0, stream);
    if (err != hipSuccess)
        (void)hipLaunchCooperativeKernel((void*)sinkhorn_all, dim3(NB), dim3(1024),
                                         (void**)args, 0, stream);
}

// Round 7
// 943.148 us; speedup vs baseline: 7.5105x; 1.2046x over previous
//
#include <hip/hip_runtime.h>
#include <hip/hip_cooperative_groups.h>

namespace cg = cooperative_groups;

typedef unsigned char u8;
typedef unsigned short u16;
typedef unsigned int u32;

#define NN 4096
#define NITER 50
#define REGE 10.0f
#define AMARG (1.0f / 4096.0f)
#define NB 256
#define KSCL 4096.0f             // K stored as Q = K * 2^12 in fp8-e5m2
#define KLN2 8.317766166719343f  // 12 * ln(2)

__device__ __forceinline__ float wsum(float v) {
#pragma unroll
    for (int off = 32; off; off >>= 1) v += __shfl_xor(v, off, 64);
    return v;
}
// e5m2 encode: f32 -> f16 (RNE) -> round mantissa to 2 bits (RNE).
__device__ __forceinline__ u8 f2e5(float f) {
    union { _Float16 h; u16 u; } cv; cv.h = (_Float16)f;
    const u16 h = cv.u;
    return (u8)((h + 0x7F + ((h >> 8) & 1)) >> 8);
}
// e5m2 = truncated fp16: decode exact (incl. subnormals)
__device__ __forceinline__ float e52f(u32 b) {
    union { u16 u; _Float16 h; } cv; cv.u = (u16)((b & 0xffu) << 8);
    return (float)cv.h;
}
__device__ __forceinline__ void dec4(u32 w, float* o) {
    o[0] = e52f(w);
    o[1] = e52f(w >> 8);
    o[2] = e52f(w >> 16);
    o[3] = e52f(w >> 24);
}

// Agent-scope (L1/L2-bypassing, L3-coherent) ops for cross-block data.
// RELAXED => no cache maintenance => private K regions stay L2-resident.
__device__ __forceinline__ float agent_ldf(const float* p) {
    return __hip_atomic_load(p, __ATOMIC_RELAXED, __HIP_MEMORY_SCOPE_AGENT);
}
__device__ __forceinline__ void agent_stf(float* p, float v) {
    __hip_atomic_store(p, v, __ATOMIC_RELAXED, __HIP_MEMORY_SCOPE_AGENT);
}
__device__ __forceinline__ int agent_ldi(const int* p) {
    return __hip_atomic_load(p, __ATOMIC_RELAXED, __HIP_MEMORY_SCOPE_AGENT);
}

// bump: all prior sc1 stores drained (syncthreads => per-wave vmcnt(0)), then +1.
__device__ __forceinline__ void bump(int* ctr, int tid) {
    __syncthreads();
    if (tid == 0) {
        asm volatile("s_waitcnt vmcnt(0)" ::: "memory");
        (void)__hip_atomic_fetch_add(ctr, 1, __ATOMIC_RELAXED, __HIP_MEMORY_SCOPE_AGENT);
    }
}
// spin until *ctr >= target (monotone counter), then block-wide release.
__device__ __forceinline__ void spin(int* ctr, int target, int tid) {
    if (tid == 0) {
        while (agent_ldi(ctr) < target) __builtin_amdgcn_s_sleep(1);
    }
    __syncthreads();
}

__global__ __launch_bounds__(1024, 4) void sinkhorn_all(
    const float* __restrict__ x, const float* __restrict__ y, float* __restrict__ out,
    u8* __restrict__ K0,
    float* __restrict__ xsq, float* __restrict__ ysq,
    float* __restrict__ ut, float* __restrict__ tpart, float* __restrict__ spart,
    float* __restrict__ lossacc, int* __restrict__ bar) {
    cg::grid_group grid = cg::this_grid();
    union Sh {
        struct { float xs[64][65]; float ys[64][65]; } bld;   // setup tiles (33 KB)
        struct {
            float uts[512];             // A: ut stripe slice
            float psumA[16][16][9];     // A: per-wave partials (padded: bank-spread)
            float vtl[128];             // vt chunk (persists to F)
            float rowsum[512];          // B: per-row sums
            float psh[16];              // F: per-wave partials
        } it;                           // ~14 KB
    };
    __shared__ Sh sh;

    const int tid  = threadIdx.x;
    const int lane = tid & 63;
    const int wid  = tid >> 6;     // 0..15
    const int b    = blockIdx.x;
    const int c    = b & 7;        // stripe: rows [512c, 512c+512)
    const int l    = b >> 3;       // 0..31: col-chunk [128l, 128l+128)

    // bar (ints): tpd[32] @0 (x16 spacing) | spd[8] @512 | utd[8] @768 | outdone @1024
    int* tpd = bar + l * 16;
    int* spd = bar + 512 + c * 16;
    int* utd = bar + 768 + c * 16;
    int* outdone = bar + 1024;

    // ---------------- S0: row norms + init ----------------
    for (int r = b * 16 + wid; r < 2 * NN; r += NB * 16) {
        const float* src = (r < NN) ? (x + (size_t)r * 64) : (y + (size_t)(r - NN) * 64);
        float t = src[lane];
        float s = wsum(t * t);
        if (lane == 0) { if (r < NN) xsq[r] = s; else ysq[r - NN] = s; }
    }
    if (tid < 16) ut[b * 16 + tid] = AMARG;   // u~ = a  (stateless scaled vars)
    if (b == 0) {
        for (int z = tid; z < 1056; z += 1024) bar[z] = 0;
        if (tid == 0) lossacc[0] = 0.f;
    }
    grid.sync();   // the ONLY grid barrier: norms/init visible, poison cleared

    // ---- S1: build Q = K*2^12 = exp2(12 - M*log2e/10) e5m2, region-private ----
    {
        const int tx = tid & 31, ty = tid >> 5;   // 32x32 threads, 2x2 out each
        for (int t = 0; t < 16; ++t) {
            const int rt = t >> 1, ct = t & 1;
            const int i0 = 512 * c + 64 * rt;
            const int j0 = 128 * l + 64 * ct;
            __syncthreads();
            {
                const int row = tid >> 4, col4 = (tid & 15) * 4;
                *(float4*)&sh.bld.xs[row][col4] = *(const float4*)(x + (size_t)(i0 + row) * 64 + col4);
                *(float4*)&sh.bld.ys[row][col4] = *(const float4*)(y + (size_t)(j0 + row) * 64 + col4);
            }
            __syncthreads();
            float a00 = 0, a01 = 0, a10 = 0, a11 = 0;
#pragma unroll
            for (int k = 0; k < 64; ++k) {
                const float x0 = sh.bld.xs[ty * 2][k],     x1 = sh.bld.xs[ty * 2 + 1][k];
                const float y0 = sh.bld.ys[tx * 2][k],     y1 = sh.bld.ys[tx * 2 + 1][k];
                a00 = __fmaf_rn(x0, y0, a00); a01 = __fmaf_rn(x0, y1, a01);
                a10 = __fmaf_rn(x1, y0, a10); a11 = __fmaf_rn(x1, y1, a11);
            }
            const float xq0 = xsq[i0 + ty * 2], xq1 = xsq[i0 + ty * 2 + 1];
            const float yq0 = ysq[j0 + tx * 2], yq1 = ysq[j0 + tx * 2 + 1];
            const float C = 0.14426950408889634f;   // log2(e)/10
            const u8 q00 = f2e5(exp2f(12.f - (xq0 + yq0 - 2.f * a00) * C));
            const u8 q01 = f2e5(exp2f(12.f - (xq0 + yq1 - 2.f * a01) * C));
            const u8 q10 = f2e5(exp2f(12.f - (xq1 + yq0 - 2.f * a10) * C));
            const u8 q11 = f2e5(exp2f(12.f - (xq1 + yq1 - 2.f * a11) * C));
            // plain stores: region is block-private => same-XCD L2, no coherence needed
            *(u16*)(K0 + (size_t)(i0 + ty * 2) * NN + j0 + tx * 2)     = (u16)(q00 | (q01 << 8));
            *(u16*)(K0 + (size_t)(i0 + ty * 2 + 1) * NN + j0 + tx * 2) = (u16)(q10 | (q11 << 8));
        }
    }
    // no sync needed: only this block reads its region

    // ------------- 50 iterations, zero grid barriers -------------
    for (int it = 0; it < NITER; ++it) {
        const int p = it & 1;   // tpart parity (double-buffered vs it-1 readers)

        // ---- A: col partials t_j over region rows; vt = 1/t ----
        {
            const int jj = tid & 15, gg = tid >> 4;   // 8 cols x 8 rows per thread
            const u8* kbase = K0 + (size_t)(512 * c + 8 * gg) * NN + 128 * l + 8 * jj;
            uint2 kr[8];
#pragma unroll
            for (int ii = 0; ii < 8; ++ii)            // private K: issue before spin
                kr[ii] = *(const uint2*)(kbase + (size_t)ii * NN);
            spin(utd, 32 * it, tid);                  // ut(it-1) stripe ready
            if (tid < 512) sh.it.uts[tid] = agent_ldf(ut + 512 * c + tid);
            __syncthreads();
            float acc[8] = {};
#pragma unroll
            for (int ii = 0; ii < 8; ++ii) {
                const float ui = sh.it.uts[8 * gg + ii];
                float qv[8];
                dec4(kr[ii].x, qv); dec4(kr[ii].y, qv + 4);
#pragma unroll
                for (int k = 0; k < 8; ++k) acc[k] = __fmaf_rn(qv[k], ui, acc[k]);
            }
#pragma unroll
            for (int k = 0; k < 8; ++k) {             // combine 4 row-groups in wave
                acc[k] += __shfl_xor(acc[k], 16, 64);
                acc[k] += __shfl_xor(acc[k], 32, 64);
            }
            if ((lane >> 4) == 0) {
#pragma unroll
                for (int k = 0; k < 8; ++k) sh.it.psumA[wid][lane][k] = acc[k];
            }
        }
        __syncthreads();
        if (tid < 128) {
            float tot = 0.f;
#pragma unroll
            for (int w = 0; w < 16; ++w) tot += sh.it.psumA[w][tid >> 3][tid & 7];
            agent_stf(tpart + ((size_t)p * 8 + c) * NN + 128 * l + tid, tot);
        }
        bump(tpd, tid);
        spin(tpd, 8 * (it + 1), tid);                 // all 8 stripe partials ready
        if (tid < 128) {
            float tq = 0.f;
#pragma unroll
            for (int cc = 0; cc < 8; ++cc)
                tq += agent_ldf(tpart + ((size_t)p * 8 + cc) * NN + 128 * l + tid);
            sh.it.vtl[tid] = 1.0f / tq;               // vt_j (stateless; eps ~ 1e-12 rel)
        }
        __syncthreads();

        // ---- B: row partials s_i over region cols (same private 64 KB) ----
        {
            const int r = tid >> 1, h = tid & 1;      // 2 threads/row, 64 cols each
            const u8* kb = K0 + (size_t)(512 * c + r) * NN + 128 * l + 64 * h;
            uint4 kq[4];
#pragma unroll
            for (int s4 = 0; s4 < 4; ++s4)
                kq[s4] = *(const uint4*)(kb + s4 * 16);
            float s = 0.f;
#pragma unroll
            for (int s4 = 0; s4 < 4; ++s4) {
                float qv[16];
                dec4(kq[s4].x, qv);      dec4(kq[s4].y, qv + 4);
                dec4(kq[s4].z, qv + 8);  dec4(kq[s4].w, qv + 12);
                const float* vp = &sh.it.vtl[64 * h + s4 * 16];
#pragma unroll
                for (int k = 0; k < 16; ++k) s = __fmaf_rn(qv[k], vp[k], s);
            }
            s += __shfl_xor(s, 1, 64);
            if (h == 0) sh.it.rowsum[r] = s;
        }
        __syncthreads();
        if (tid < 512)   // spart[c][row][l'] : scatter on store, coalesced on read
            agent_stf(spart + ((size_t)c * 512 + tid) * 32 + l, sh.it.rowsum[tid]);
        bump(spd, tid);
        spin(spd, 32 * (it + 1), tid);                // all 32 chunk partials ready
        if (tid < 512) {
            const int rl = tid >> 5, lp = tid & 31;   // my 16 rows [16l,16l+16)
            float sp = agent_ldf(spart + ((size_t)c * 512 + 16 * l + rl) * 32 + lp);
#pragma unroll
            for (int off = 1; off < 32; off <<= 1) sp += __shfl_xor(sp, off, 64);
            if (lp == 0) agent_stf(ut + 512 * c + 16 * l + rl, 1.0f / sp);  // ut_i
        }
        bump(utd, tid);
    }

    // ------ F: loss = sum_ij K*(-eps log K)*ut_i*vt_j over own region ------
    // per element: (-eps/KSCL) * Q*(lnQ - 12ln2) * ut_i * vt_j ; vtl = final vt chunk
    spin(utd, 32 * NITER, tid);                       // final ut stripe ready
    {
        const int r = tid >> 1, h = tid & 1;
        const int i = 512 * c + r;
        const u8* kb = K0 + (size_t)i * NN + 128 * l + 64 * h;
        uint4 kq[4];
#pragma unroll
        for (int s4 = 0; s4 < 4; ++s4)
            kq[s4] = *(const uint4*)(kb + s4 * 16);
        float a1 = 0.f, a2 = 0.f;
#pragma unroll
        for (int s4 = 0; s4 < 4; ++s4) {
            float qv[16];
            dec4(kq[s4].x, qv);      dec4(kq[s4].y, qv + 4);
            dec4(kq[s4].z, qv + 8);  dec4(kq[s4].w, qv + 12);
            const float* vp = &sh.it.vtl[64 * h + s4 * 16];
#pragma unroll
            for (int k = 0; k < 16; ++k) {
                const float q = qv[k];
                a2 = __fmaf_rn(q, vp[k], a2);
                a1 = __fmaf_rn(q * __logf(fmaxf(q, 1e-30f)), vp[k], a1);  // q=0 -> 0
            }
        }
        a1 += __shfl_xor(a1, 1, 64);
        a2 += __shfl_xor(a2, 1, 64);
        float rowv = (h == 0) ? (a1 - KLN2 * a2) * agent_ldf(ut + i) : 0.f;
        rowv = wsum(rowv);
        if (lane == 0) sh.it.psh[wid] = rowv;
    }
    __syncthreads();
    if (tid == 0) {
        float bacc = 0.f;
#pragma unroll
        for (int w = 0; w < 16; ++w) bacc += sh.it.psh[w];
        (void)__hip_atomic_fetch_add(lossacc, bacc, __ATOMIC_RELAXED,
                                     __HIP_MEMORY_SCOPE_AGENT);
        asm volatile("s_waitcnt vmcnt(0)" ::: "memory");
        const int old = __hip_atomic_fetch_add(outdone, 1,
                                               __ATOMIC_RELAXED, __HIP_MEMORY_SCOPE_AGENT);
        if (old == NB - 1) {   // all 256 contributions are in lossacc
            out[0] = agent_ldf(lossacc) * (-REGE / KSCL);
        }
    }
}

extern "C" void kernel_launch(void* const* d_in, const int* in_sizes, int n_in,
                              void* d_out, int out_size, void* d_ws, size_t ws_size,
                              hipStream_t stream) {
    const float* x = (const float*)d_in[0];
    const float* y = (const float*)d_in[1];
    float* out = (float*)d_out;
    char* ws = (char*)d_ws;

    // ws: K0 e5m2 16MB | xsq,ysq,ut (4096 ea) | tpart 2x8x4096 | spart 8x512x32 |
    //     lossacc | bar 1056 ints
    u8* K0 = (u8*)(ws);
    float* fb = (float*)(ws + 16777216ull);
    float* xsq = fb + 0 * 4096;
    float* ysq = fb + 1 * 4096;
    float* ut  = fb + 2 * 4096;
    float* tpart = fb + 3 * 4096;                 // 2*8*4096 = 65536 floats
    float* spart = fb + 19 * 4096;                // 8*512*32 = 131072 floats
    float* lossacc = fb + 51 * 4096;              // 1 float (16-pad)
    int*   bar     = (int*)(fb + 51 * 4096 + 16);

    void* args[] = {&x, &y, &out, &K0, &xsq, &ysq, &ut, &tpart, &spart, &lossacc, &bar};

    hipError_t err = hipLaunchCooperativeKernel((void*)sinkhorn_all, dim3(NB), dim3(1024),
                                                (void**)args, 0, stream);
    if (err != hipSuccess)
        (void)hipLaunchCooperativeKernel((void*)sinkhorn_all, dim3(NB), dim3(1024),
                                         (void**)args, 0, stream);
}